// Round 8
// baseline (581.021 us; speedup 1.0000x reference)
//
#include <hip/hip_runtime.h>

#define NN 5000
#define NE 50000
#define LL 9
#define CC 128
#define NH 8
#define VCD 16
#define DR 128
#define AE 64
#define MZ 100

typedef unsigned int u32;
typedef unsigned short u16;

typedef __attribute__((ext_vector_type(8))) short bf16x8;
typedef __attribute__((ext_vector_type(4))) float f32x4;

__device__ __forceinline__ bf16x8 as_bf16x8(uint4 v){
  union { uint4 u; bf16x8 b; } x; x.u = v; return x.b;
}

// ---------- bf16 helpers ----------
__device__ __forceinline__ float bf_lo(u32 u){ return __uint_as_float(u << 16); }
__device__ __forceinline__ float bf_hi(u32 u){ return __uint_as_float(u & 0xffff0000u); }
__device__ __forceinline__ u16 f2bf(float f){
  u32 u = __float_as_uint(f);
  u32 r = (u + 0x7fffu + ((u >> 16) & 1u)) >> 16;  // RNE
  return (u16)r;
}
__device__ __forceinline__ u32 pack2(float a, float b){
  return (u32)f2bf(a) | ((u32)f2bf(b) << 16);
}
__device__ __forceinline__ u32 encf(float f){
  u32 u = __float_as_uint(f);
  return (u & 0x80000000u) ? ~u : (u | 0x80000000u);
}
__device__ __forceinline__ float decf(u32 k){
  u32 u = (k & 0x80000000u) ? (k & 0x7fffffffu) : ~k;
  return __uint_as_float(u);
}
__device__ __forceinline__ float sigmoidf_(float x){ return 1.f / (1.f + __expf(-x)); }

// ---------- K0: tables + zero-init + K-major weight transposes for MFMA ----------
__global__ void k0_tables(const float* __restrict__ ae_v, const float* __restrict__ wr1_v,
                          const float* __restrict__ ae_d, const float* __restrict__ wr1_d,
                          const float* __restrict__ wval_v, const float* __restrict__ wproj_v,
                          const float* __restrict__ wval_d, const float* __restrict__ wproj_d,
                          const float* __restrict__ wmsg_v, const float* __restrict__ wmsg_d,
                          const float* __restrict__ wal_v, const float* __restrict__ wal_d,
                          const float* __restrict__ wr2_v, const float* __restrict__ wr2_d,
                          float* __restrict__ radz, float* __restrict__ wpv,
                          u32* __restrict__ mkey, float* __restrict__ den,
                          float* __restrict__ acc, u32* __restrict__ cnt,
                          u32* __restrict__ WtM, u32* __restrict__ WtA,
                          u32* __restrict__ WtR1, u32* __restrict__ WtR2)
{
  int idx = blockIdx.x * 256 + threadIdx.x;
  if (idx < 2 * 2 * MZ * CC) {   // radz[tag][sd][z][c]
    int c = idx & 127;
    int z = (idx >> 7) % MZ;
    int sd = (idx / (128 * MZ)) & 1;
    int tag = idx / (128 * MZ * 2);
    const float* ae = tag ? ae_d : ae_v;
    const float* w  = tag ? wr1_d : wr1_v;
    float s = 0.f;
    for (int a = 0; a < AE; ++a)
      s += ae[z * AE + a] * w[(DR + sd * AE + a) * CC + c];
    radz[idx] = s;
  }
  int i2 = idx - 2 * 2 * MZ * CC;
  if (i2 >= 0 && i2 < 2 * CC * NH) {   // wpv[tag][c][h]
    int h = i2 & 7;
    int c = (i2 >> 3) & 127;
    int tag = i2 >> 10;
    const float* wv = tag ? wval_d : wval_v;
    const float* wp = tag ? wproj_d : wproj_v;
    float s = 0.f;
    for (int q = 0; q < VCD; ++q) s += wv[c * (NH * VCD) + h * VCD + q] * wp[h * VCD + q];
    wpv[i2] = s;
  }
  int i3 = i2 - 2 * CC * NH;
  if (i3 >= 0 && i3 < 2 * NN * NH) mkey[i3] = 0u;
  int i4 = i3 - 2 * NN * NH;
  if (i4 >= 0 && i4 < 2 * NN * NH) den[i4] = 0.f;
  int i5 = i4 - 2 * NN * NH;
  if (i5 >= 0 && i5 < 2 * NN * 3) acc[i5] = 0.f;
  int i6 = i5 - 2 * NN * 3;
  if (i6 >= 0 && i6 < NN) cnt[i6] = 0u;
  int i7 = i6 - NN;
  if (i7 >= 0 && i7 < 4 * 128 * 64) {   // WtM[chunk][col][kp]
    int chunk = i7 >> 13;
    int col = (i7 >> 6) & 127;
    int kp = i7 & 63;
    const float* Wm = (chunk >= 2) ? wmsg_d : wmsg_v;
    int kb = 128 * (chunk & 1);
    WtM[i7] = pack2(Wm[(kb + 2 * kp) * 128 + col], Wm[(kb + 2 * kp + 1) * 128 + col]);
  }
  int i8 = i7 - 4 * 128 * 64;
  if (i8 >= 0 && i8 < 2 * 256 * 64) {   // WtA[tag][col][kp]
    int tag = i8 >> 14;
    int col = (i8 >> 6) & 255;
    int kp = i8 & 63;
    const float* Wa = tag ? wal_d : wal_v;
    WtA[i8] = pack2(Wa[(2 * kp) * 256 + col], Wa[(2 * kp + 1) * 256 + col]);
  }
  int i9 = i8 - 2 * 256 * 64;
  if (i9 >= 0 && i9 < 2 * 128 * 64) {   // WtR1[tag][col][kp]
    int tag = i9 >> 13;
    int col = (i9 >> 6) & 127;
    int kp = i9 & 63;
    const float* W = tag ? wr1_d : wr1_v;
    WtR1[i9] = pack2(W[(2 * kp) * 128 + col], W[(2 * kp + 1) * 128 + col]);
  }
  int i10 = i9 - 2 * 128 * 64;
  if (i10 >= 0 && i10 < 2 * 128 * 64) {   // WtR2[tag][col][kp]
    int tag = i10 >> 13;
    int col = (i10 >> 6) & 127;
    int kp = i10 & 63;
    const float* W = tag ? wr2_d : wr2_v;
    WtR2[i10] = pack2(W[(2 * kp) * 128 + col], W[(2 * kp + 1) * 128 + col]);
  }
}

// ---------- K0b: detect mask storage format ----------
__global__ void k0_flag(const u32* __restrict__ mw, int* __restrict__ flag)
{
  __shared__ int bad;
  if (threadIdx.x == 0) bad = 0;
  __syncthreads();
  int lbad = 0;
  for (int i = threadIdx.x; i < 1248; i += 256)
    if (mw[i] > 1u) lbad = 1;
  if (lbad) bad = 1;
  __syncthreads();
  if (threadIdx.x == 0) *flag = bad;   // 1 => bytes, 0 => int32
}

// ---------- sort: histogram / scan / scatter (counting sort by dst) ----------
__global__ void ks_hist(const int* __restrict__ eidx, u32* __restrict__ cnt)
{
  int idx = blockIdx.x * 256 + threadIdx.x;
  if (idx < NE) atomicAdd(&cnt[eidx[NE + idx]], 1u);
}

__global__ void ks_scan(u32* __restrict__ cnt)   // in-place exclusive prefix, 1 block
{
  __shared__ u32 tsum[256];
  int t = threadIdx.x;
  u32 loc[20];
  u32 s = 0;
  #pragma unroll
  for (int k = 0; k < 20; ++k) {
    int b = t * 20 + k;
    loc[k] = (b < NN) ? cnt[b] : 0u;
    s += loc[k];
  }
  tsum[t] = s;
  __syncthreads();
  for (int off = 1; off < 256; off <<= 1) {
    u32 v = (t >= off) ? tsum[t - off] : 0u;
    __syncthreads();
    tsum[t] += v;
    __syncthreads();
  }
  u32 base = (t == 0) ? 0u : tsum[t - 1];
  #pragma unroll
  for (int k = 0; k < 20; ++k) {
    int b = t * 20 + k;
    if (b < NN) cnt[b] = base;
    base += loc[k];
  }
}

__global__ void ks_scatter(const int* __restrict__ eidx, u32* __restrict__ base,
                           u32* __restrict__ eperm, int* __restrict__ ssrc, int* __restrict__ sdst)
{
  int idx = blockIdx.x * 256 + threadIdx.x;
  if (idx >= NE) return;
  int d = eidx[NE + idx];
  u32 pos = atomicAdd(&base[d], 1u);
  eperm[pos] = (u32)idx;
  ssrc[pos] = eidx[idx];
  sdst[pos] = d;
}

// ---------- K1 (MFMA): P = x @ W_msg halves; 32 rows x 512 cols per block ----------
__global__ __launch_bounds__(256) void k1_nodepre(const float* __restrict__ x,
                                                  const u32* __restrict__ WtM,
                                                  u32* __restrict__ P32)
{
  __shared__ uint4 As4[32 * 17];
  u32* As = (u32*)As4;
  int t = threadIdx.x;
  int row0 = blockIdx.x * 32;
  for (int i = t; i < 32 * 64; i += 256) {
    int r = i >> 6, cp = i & 63;
    int row = row0 + r;
    u32 v = 0u;
    if (row < NN * LL) {
      float2 xv = *(const float2*)(x + (size_t)row * CC + 2 * cp);
      v = pack2(xv.x, xv.y);
    }
    As[r * 68 + cp] = v;
  }
  __syncthreads();
  int w = t >> 6, lane = t & 63;
  int m = lane & 15, kb = lane >> 4;
  int r16 = 16 * (w & 1);
  int cb = 256 * (w >> 1);
  bf16x8 afr[4];
  #pragma unroll
  for (int ks = 0; ks < 4; ++ks)
    afr[ks] = as_bf16x8(*(const uint4*)&As[(r16 + m) * 68 + ks * 16 + kb * 4]);
  int rowbase = row0 + r16;
  for (int ct = 0; ct < 16; ++ct) {
    int col = cb + ct * 16 + m;          // 0..511
    int chunk = col >> 7;
    int cl = col & 127;
    f32x4 accv = {0.f, 0.f, 0.f, 0.f};
    #pragma unroll
    for (int ks = 0; ks < 4; ++ks) {
      bf16x8 bfr = as_bf16x8(*(const uint4*)(WtM + ((size_t)chunk * 128 + cl) * 64 + ks * 16 + kb * 4));
      accv = __builtin_amdgcn_mfma_f32_16x16x32_bf16(afr[ks], bfr, accv, 0, 0, 0);
    }
    #pragma unroll
    for (int reg = 0; reg < 4; ++reg) {
      float v = accv[reg];
      float vv = __shfl_xor(v, 1, 64);
      int row = rowbase + kb * 4 + reg;
      if (((lane & 1) == 0) && row < NN * LL) {
        int n = row / 9, j = row - n * 9;
        P32[((size_t)n * 4 + chunk) * 576 + j * 64 + (cl >> 1)] = pack2(v, vv);
      }
    }
  }
}

// ---------- K23 (MFMA): rad = W_rad2( silu(edist@W_rad1 + radz_s + radz_d) ), fused ----------
__global__ __launch_bounds__(256) void k23_rad(const float* __restrict__ edist,
                                               const u32* __restrict__ WtR1,
                                               const u32* __restrict__ WtR2,
                                               const u32* __restrict__ eperm,
                                               const int* __restrict__ ssrc,
                                               const int* __restrict__ sdst,
                                               const int* __restrict__ zn,
                                               const float* __restrict__ radz,
                                               u32* __restrict__ h1rad)
{
  __shared__ uint4 As4[32 * 17];
  __shared__ uint4 Hs4[32 * 17];
  u32* As = (u32*)As4;
  u32* Hs = (u32*)Hs4;
  __shared__ int zsS[32], zdS[32];
  __shared__ u32 epS[32];
  int t = threadIdx.x;
  int tag = blockIdx.y;
  int e0 = blockIdx.x * 32;
  if (t < 32) {
    int e = e0 + t;
    u32 ep = 0; int s = 0, d = 0;
    if (e < NE) { ep = eperm[e]; s = ssrc[e]; d = sdst[e]; }
    epS[t] = ep; zsS[t] = zn[s]; zdS[t] = zn[d];
  }
  __syncthreads();
  for (int i = t; i < 32 * 64; i += 256) {
    int r = i >> 6, cp = i & 63;
    u32 v = 0u;
    if (e0 + r < NE) {
      float2 xv = *(const float2*)(edist + (size_t)epS[r] * DR + 2 * cp);
      v = pack2(xv.x, xv.y);
    }
    As[r * 68 + cp] = v;
  }
  __syncthreads();
  int w = t >> 6, lane = t & 63;
  int m = lane & 15, kb = lane >> 4;
  int r16 = 16 * (w & 1);
  int cb = 64 * (w >> 1);
  const float* rz_s = radz + tag * 2 * MZ * CC;
  const float* rz_d = rz_s + MZ * CC;
  {  // GEMM1 + radz + silu -> Hs (bf16)
    bf16x8 afr[4];
    #pragma unroll
    for (int ks = 0; ks < 4; ++ks)
      afr[ks] = as_bf16x8(*(const uint4*)&As[(r16 + m) * 68 + ks * 16 + kb * 4]);
    const u32* B1 = WtR1 + (size_t)tag * 128 * 64;
    #pragma unroll
    for (int ct = 0; ct < 4; ++ct) {
      int col = cb + ct * 16 + m;
      f32x4 accv = {0.f, 0.f, 0.f, 0.f};
      #pragma unroll
      for (int ks = 0; ks < 4; ++ks) {
        bf16x8 bfr = as_bf16x8(*(const uint4*)(B1 + (size_t)col * 64 + ks * 16 + kb * 4));
        accv = __builtin_amdgcn_mfma_f32_16x16x32_bf16(afr[ks], bfr, accv, 0, 0, 0);
      }
      #pragma unroll
      for (int reg = 0; reg < 4; ++reg) {
        int row = r16 + kb * 4 + reg;
        float v = accv[reg] + rz_s[zsS[row] * CC + col] + rz_d[zdS[row] * CC + col];
        v = v * sigmoidf_(v);
        float vv = __shfl_xor(v, 1, 64);
        if ((m & 1) == 0) Hs[row * 68 + (col >> 1)] = pack2(v, vv);
      }
    }
  }
  __syncthreads();
  {  // GEMM2 -> h1rad (bf16, sorted layout)
    bf16x8 afr[4];
    #pragma unroll
    for (int ks = 0; ks < 4; ++ks)
      afr[ks] = as_bf16x8(*(const uint4*)&Hs[(r16 + m) * 68 + ks * 16 + kb * 4]);
    const u32* B2 = WtR2 + (size_t)tag * 128 * 64;
    #pragma unroll
    for (int ct = 0; ct < 4; ++ct) {
      int col = cb + ct * 16 + m;
      f32x4 accv = {0.f, 0.f, 0.f, 0.f};
      #pragma unroll
      for (int ks = 0; ks < 4; ++ks) {
        bf16x8 bfr = as_bf16x8(*(const uint4*)(B2 + (size_t)col * 64 + ks * 16 + kb * 4));
        accv = __builtin_amdgcn_mfma_f32_16x16x32_bf16(afr[ks], bfr, accv, 0, 0, 0);
      }
      #pragma unroll
      for (int reg = 0; reg < 4; ++reg) {
        int row = r16 + kb * 4 + reg;
        int e = e0 + row;
        float v = accv[reg];
        float vv = __shfl_xor(v, 1, 64);
        if (((m & 1) == 0) && e < NE)
          h1rad[((size_t)tag * NE + e) * 64 + (col >> 1)] = pack2(v, vv);
      }
    }
  }
}

// ---------- KF: fused single-gather {logits+mkey} + {attn-independent T} ----------
__global__ __launch_bounds__(256) void kF(const u32* __restrict__ P32,
                                          const float* __restrict__ wig,
                                          const u32* __restrict__ h1rad,
                                          const u32* __restrict__ WtA,
                                          const float* __restrict__ av_v,
                                          const float* __restrict__ av_d,
                                          const float* __restrict__ wpv,
                                          const u32* __restrict__ eperm,
                                          const int* __restrict__ ssrc,
                                          const int* __restrict__ sdst,
                                          float* __restrict__ logits,
                                          u32* __restrict__ mkey,
                                          float* __restrict__ Tbuf)
{
  __shared__ uint4 As4[32 * 17];
  u32* As = (u32*)As4;
  __shared__ float wigS[32][82];
  __shared__ int es_s[32], ed_s[32];
  __shared__ u32 ep_s[32];
  __shared__ float ltile[32][8];
  __shared__ float wpvS[1024];
  int t = threadIdx.x;
  int tag = blockIdx.y;
  const float* av = tag ? av_d : av_v;
  int i0 = blockIdx.x * 32;
  if (t < 32) {
    int i = i0 + t;
    int s = 0, d = 0; u32 ep = 0;
    if (i < NE) { s = ssrc[i]; d = sdst[i]; ep = eperm[i]; }
    es_s[t] = s; ed_s[t] = d; ep_s[t] = ep;
  }
  for (int q = t; q < 1024; q += 256) wpvS[q] = wpv[tag * 1024 + q];
  __syncthreads();
  for (int q = t; q < 32 * 81; q += 256) {
    int el = q / 81, j = q - el * 81;
    wigS[el][j] = (i0 + el < NE) ? wig[(size_t)ep_s[el] * 81 + j] : 0.f;
  }
  __syncthreads();
  int w = t >> 6, lane = t & 63;
  // ---------- phase 1: per-edge full combine, T output, As row-0 build ----------
  for (int k = 0; k < 8; ++k) {
    int el = w * 8 + k;
    int i = i0 + el;
    bool ok = (i < NE);
    float S0[9], S1[9];
    #pragma unroll
    for (int j = 0; j < 9; ++j) { S0[j] = 0.f; S1[j] = 0.f; }
    float r0v = 0.f, r1v = 0.f;
    if (ok) {
      const u32* rowT = P32 + ((size_t)es_s[el] * 4 + tag * 2) * 576;
      const u32* rowB = P32 + ((size_t)ed_s[el] * 4 + tag * 2 + 1) * 576;
      #pragma unroll
      for (int j = 0; j < 9; ++j) {
        u32 a = rowT[j * 64 + lane];
        u32 b = rowB[j * 64 + lane];
        S0[j] = bf_lo(a) + bf_lo(b);
        S1[j] = bf_hi(a) + bf_hi(b);
      }
      u32 ur = h1rad[((size_t)tag * NE + i) * 64 + lane];
      r0v = bf_lo(ur); r1v = bf_hi(ur);
    }
    float m0[9], m1[9];
    #pragma unroll
    for (int r = 0; r < 9; ++r) {
      float a0 = 0.f, a1 = 0.f;
      #pragma unroll
      for (int j = 0; j < 9; ++j) {
        float wv = wigS[el][r * 9 + j];
        a0 += wv * S0[j];
        a1 += wv * S1[j];
      }
      m0[r] = a0 * r0v;
      m1[r] = a1 * r1v;
    }
    As[el * 68 + lane] = pack2(m0[0], m1[0]);      // logits A-row (bf16)
    float g0 = sigmoidf_(m0[0]);
    float g1 = sigmoidf_(m1[0]);
    float Wp[3][8];
    #pragma unroll
    for (int i3 = 0; i3 < 3; ++i3)
      #pragma unroll
      for (int h = 0; h < 8; ++h) Wp[i3][h] = 0.f;
    #pragma unroll
    for (int j = 0; j < 9; ++j) {
      float v0 = m0[j] * g0, v1 = m1[j] * g1;     // val (row0 = silu, rows>=1 gated)
      float vw[8];
      #pragma unroll
      for (int h = 0; h < 8; ++h)
        vw[h] = v0 * wpvS[(2 * lane) * 8 + h] + v1 * wpvS[(2 * lane + 1) * 8 + h];
      float wo1 = wigS[el][j * 9 + 1];
      float wo2 = wigS[el][j * 9 + 2];
      float wo3 = wigS[el][j * 9 + 3];
      #pragma unroll
      for (int h = 0; h < 8; ++h) {
        Wp[0][h] += wo1 * vw[h];
        Wp[1][h] += wo2 * vw[h];
        Wp[2][h] += wo3 * vw[h];
      }
    }
    #pragma unroll
    for (int off = 1; off < 64; off <<= 1)
      #pragma unroll
      for (int i3 = 0; i3 < 3; ++i3)
        #pragma unroll
        for (int h = 0; h < 8; ++h)
          Wp[i3][h] += __shfl_xor(Wp[i3][h], off, 64);
    if (lane == 0 && ok) {
      float* Tp = Tbuf + ((size_t)tag * NE + i) * 24;
      #pragma unroll
      for (int h = 0; h < 8; ++h) {
        Tp[h * 3 + 0] = Wp[0][h];
        Tp[h * 3 + 1] = Wp[1][h];
        Tp[h * 3 + 2] = Wp[2][h];
      }
    }
  }
  __syncthreads();
  // ---------- phase 2: MFMA logits C(32x256) = A(32x128) @ WtA ----------
  {
    int m = lane & 15, kb = lane >> 4;
    int r16 = 16 * (w & 1);
    int cb = 128 * (w >> 1);
    bf16x8 afr[4];
    #pragma unroll
    for (int ks = 0; ks < 4; ++ks)
      afr[ks] = as_bf16x8(*(const uint4*)&As[(r16 + m) * 68 + ks * 16 + kb * 4]);
    const u32* WA = WtA + (size_t)tag * 256 * 64;
    float psum[4][4];
    #pragma unroll
    for (int a = 0; a < 4; ++a)
      #pragma unroll
      for (int b = 0; b < 4; ++b) psum[a][b] = 0.f;
    #pragma unroll
    for (int ct = 0; ct < 8; ++ct) {
      int col = cb + ct * 16 + m;
      f32x4 accv = {0.f, 0.f, 0.f, 0.f};
      #pragma unroll
      for (int ks = 0; ks < 4; ++ks) {
        bf16x8 bfr = as_bf16x8(*(const uint4*)(WA + (size_t)col * 64 + ks * 16 + kb * 4));
        accv = __builtin_amdgcn_mfma_f32_16x16x32_bf16(afr[ks], bfr, accv, 0, 0, 0);
      }
      int hl = ct >> 1;
      float avv = av[(4 * (w >> 1) + hl) * 32 + (ct & 1) * 16 + m];
      #pragma unroll
      for (int reg = 0; reg < 4; ++reg) {
        float aa = accv[reg];
        aa = (aa >= 0.f) ? aa : 0.2f * aa;    // leaky_relu 0.2
        psum[hl][reg] += aa * avv;
      }
    }
    #pragma unroll
    for (int hl = 0; hl < 4; ++hl) {
      #pragma unroll
      for (int reg = 0; reg < 4; ++reg) {
        float v = psum[hl][reg];
        v += __shfl_xor(v, 1, 64);
        v += __shfl_xor(v, 2, 64);
        v += __shfl_xor(v, 4, 64);
        v += __shfl_xor(v, 8, 64);
        if (m == 0) ltile[r16 + kb * 4 + reg][4 * (w >> 1) + hl] = v;
      }
    }
  }
  __syncthreads();
  {
    int el = t >> 3, hh = t & 7;
    int i = i0 + el;
    if (i < NE) {
      float lg = ltile[el][hh];
      logits[((size_t)tag * NE + i) * NH + hh] = lg;
      atomicMax(&mkey[tag * NN * NH + ed_s[el] * NH + hh], encf(lg));
    }
  }
}

// ---------- K5: ex = exp(logit - m[dst]); den = segment_sum (sorted order) ----------
__global__ void k5_ex(const float* __restrict__ logits, const u32* __restrict__ mkey,
                      const int* __restrict__ sdst, float* __restrict__ ex, float* __restrict__ den)
{
  int idx = blockIdx.x * 256 + threadIdx.x;
  if (idx >= 2 * NE * NH) return;
  int h = idx & 7;
  int e = (idx >> 3) % NE;
  int tag = idx / (NE * NH);
  int d = sdst[e];
  float m = decf(mkey[tag * NN * NH + d * NH + h]);
  float v = __expf(logits[idx] - m);
  ex[idx] = v;
  atomicAdd(&den[tag * NN * NH + d * NH + h], v);
}

// ---------- K6s: out contribution = sum_h attn * T, no P traffic ----------
__global__ void k6_scatter(const float* __restrict__ ex, const float* __restrict__ den,
                           const float* __restrict__ Tbuf, const int* __restrict__ sdst,
                           float* __restrict__ acc)
{
  int idx = blockIdx.x * 256 + threadIdx.x;
  if (idx >= 2 * NE) return;
  int tag = idx / NE;
  int e = idx - tag * NE;
  int d = sdst[e];
  const float* Tp = Tbuf + ((size_t)tag * NE + e) * 24;
  float y0 = 0.f, y1 = 0.f, y2 = 0.f;
  #pragma unroll
  for (int h = 0; h < 8; ++h) {
    float at = ex[((size_t)tag * NE + e) * 8 + h]
             / (den[tag * NN * NH + d * NH + h] + 1e-9f);
    y0 += at * Tp[h * 3 + 0];
    y1 += at * Tp[h * 3 + 1];
    y2 += at * Tp[h * 3 + 2];
  }
  atomicAdd(&acc[tag * NN * 3 + d * 3 + 0], y0);
  atomicAdd(&acc[tag * NN * 3 + d * 3 + 1], y1);
  atomicAdd(&acc[tag * NN * 3 + d * 3 + 2], y2);
}

// ---------- K7: masked select, f32 out ----------
__global__ void k7_out(const float* __restrict__ acc, const void* __restrict__ mask,
                       const int* __restrict__ flag, float* __restrict__ out)
{
  int idx = blockIdx.x * 256 + threadIdx.x;
  if (idx >= NN * 3) return;
  int n = idx / 3;
  bool msk;
  if (*flag) msk = ((const unsigned char*)mask)[n] != 0;
  else       msk = ((const int*)mask)[n] != 0;
  out[idx] = msk ? acc[NN * 3 + idx] : acc[idx];
}

extern "C" void kernel_launch(void* const* d_in, const int* in_sizes, int n_in,
                              void* d_out, int out_size, void* d_ws, size_t ws_size,
                              hipStream_t stream)
{
  (void)hipGetLastError();   // clear sticky error state

  bool setup_order = (n_in >= 22) && (in_sizes[3] == NN) && (in_sizes[4] == 2 * NE);
  const float *x, *edist, *wig;
  const int *zn, *eidx;
  const void *mask;
  const float *ae_v, *wr1_v, *wr2_v, *wmsg_v, *wal_v, *av_v, *wval_v, *wproj_v;
  const float *ae_d, *wr1_d, *wr2_d, *wmsg_d, *wal_d, *av_d, *wval_d, *wproj_d;
  x     = (const float*)d_in[0];
  edist = (const float*)d_in[1];
  wig   = (const float*)d_in[2];
  if (setup_order) {
    zn      = (const int*)d_in[3];
    eidx    = (const int*)d_in[4];
    mask    = d_in[5];
    ae_v    = (const float*)d_in[6];   wr1_v  = (const float*)d_in[7];
    wr2_v   = (const float*)d_in[8];   wmsg_v = (const float*)d_in[9];
    wal_v   = (const float*)d_in[10];  av_v   = (const float*)d_in[11];
    wval_v  = (const float*)d_in[12];  wproj_v= (const float*)d_in[13];
    ae_d    = (const float*)d_in[14];  wr1_d  = (const float*)d_in[15];
    wr2_d   = (const float*)d_in[16];  wmsg_d = (const float*)d_in[17];
    wal_d   = (const float*)d_in[18];  av_d   = (const float*)d_in[19];
    wval_d  = (const float*)d_in[20];  wproj_d= (const float*)d_in[21];
  } else {
    ae_v    = (const float*)d_in[3];   wr1_v  = (const float*)d_in[4];
    wr2_v   = (const float*)d_in[5];   wmsg_v = (const float*)d_in[6];
    wal_v   = (const float*)d_in[7];   av_v   = (const float*)d_in[8];
    wval_v  = (const float*)d_in[9];   wproj_v= (const float*)d_in[10];
    ae_d    = (const float*)d_in[11];  wr1_d  = (const float*)d_in[12];
    wr2_d   = (const float*)d_in[13];  wmsg_d = (const float*)d_in[14];
    wal_d   = (const float*)d_in[15];  av_d   = (const float*)d_in[16];
    wval_d  = (const float*)d_in[17];  wproj_d= (const float*)d_in[18];
    zn      = (const int*)d_in[19];
    eidx    = (const int*)d_in[20];
    mask    = d_in[21];
  }

  // ---- workspace layout (bytes) ----
  const size_t OFF_P    = 0;              // 46,080,000
  const size_t OFF_H1   = 46080000;       // 25,600,000
  const size_t OFF_LOG  = 71680000;       //  3,200,000
  const size_t OFF_EX   = 74880000;       //  3,200,000
  const size_t OFF_T    = 78080000;       //  9,600,000 (2*NE*24 f32)
  const size_t OFF_MK   = 87680000;       //    320,000
  const size_t OFF_DEN  = 88000000;       //    320,000
  const size_t OFF_ACC  = 88320000;       //    120,000
  const size_t OFF_RADZ = 88440000;       //    204,800
  const size_t OFF_WPV  = 88644800;       //      8,192
  const size_t OFF_FLAG = 88652992;       //         64
  const size_t OFF_CNT  = 88653056;       //     20,000
  const size_t OFF_PERM = 88673056;       //    200,000
  const size_t OFF_SSRC = 88873056;       //    200,000
  const size_t OFF_SDST = 89073056;       //    200,000
  const size_t OFF_WTM  = 89273056;       //    131,072
  const size_t OFF_WTA  = 89404128;       //    131,072
  const size_t OFF_WTR1 = 89535200;       //     65,536
  const size_t OFF_WTR2 = 89600736;       //     65,536
  const size_t NEEDED   = 89666272;

  const size_t out_bytes = (size_t)out_size * sizeof(float);

  if (d_ws == nullptr || ws_size < NEEDED) {
    hipMemsetAsync(d_out, 0x66, out_bytes, stream);   // ws-too-small signature
    return;
  }

  char* ws = (char*)d_ws;
  u32*   P32    = (u32*)(ws + OFF_P);
  u32*   h1rad  = (u32*)(ws + OFF_H1);
  float* logits = (float*)(ws + OFF_LOG);
  float* ex     = (float*)(ws + OFF_EX);
  float* Tbuf   = (float*)(ws + OFF_T);
  u32*   mkey   = (u32*)(ws + OFF_MK);
  float* den    = (float*)(ws + OFF_DEN);
  float* acc    = (float*)(ws + OFF_ACC);
  float* radz   = (float*)(ws + OFF_RADZ);
  float* wpv    = (float*)(ws + OFF_WPV);
  int*   flag   = (int*)(ws + OFF_FLAG);
  u32*   cnt    = (u32*)(ws + OFF_CNT);
  u32*   eperm  = (u32*)(ws + OFF_PERM);
  int*   ssrc   = (int*)(ws + OFF_SSRC);
  int*   sdst   = (int*)(ws + OFF_SDST);
  u32*   WtM    = (u32*)(ws + OFF_WTM);
  u32*   WtA    = (u32*)(ws + OFF_WTA);
  u32*   WtR1   = (u32*)(ws + OFF_WTR1);
  u32*   WtR2   = (u32*)(ws + OFF_WTR2);

  k0_tables<<<1354, 256, 0, stream>>>(ae_v, wr1_v, ae_d, wr1_d,
                                      wval_v, wproj_v, wval_d, wproj_d,
                                      wmsg_v, wmsg_d, wal_v, wal_d,
                                      wr2_v, wr2_d,
                                      radz, wpv, mkey, den, acc, cnt,
                                      WtM, WtA, WtR1, WtR2);
  k0_flag<<<1, 256, 0, stream>>>((const u32*)mask, flag);
  ks_hist<<<196, 256, 0, stream>>>(eidx, cnt);
  ks_scan<<<1, 256, 0, stream>>>(cnt);
  ks_scatter<<<196, 256, 0, stream>>>(eidx, cnt, eperm, ssrc, sdst);
  k1_nodepre<<<1407, 256, 0, stream>>>(x, WtM, P32);
  k23_rad<<<dim3(1563, 2), 256, 0, stream>>>(edist, WtR1, WtR2, eperm, ssrc, sdst,
                                             zn, radz, h1rad);
  kF<<<dim3(1563, 2), 256, 0, stream>>>(P32, wig, h1rad, WtA, av_v, av_d, wpv,
                                        eperm, ssrc, sdst, logits, mkey, Tbuf);
  k5_ex<<<3125, 256, 0, stream>>>(logits, mkey, sdst, ex, den);
  k6_scatter<<<391, 256, 0, stream>>>(ex, den, Tbuf, sdst, acc);
  k7_out<<<59, 256, 0, stream>>>(acc, mask, flag, (float*)d_out);

  if (hipGetLastError() != hipSuccess) {
    hipMemsetAsync(d_out, 0x77, out_bytes, stream);   // launch-failure signature
  }
}

// Round 9
// 558.162 us; speedup vs baseline: 1.0410x; 1.0410x over previous
//
#include <hip/hip_runtime.h>

#define NN 5000
#define NE 50000
#define LL 9
#define CC 128
#define NH 8
#define VCD 16
#define DR 128
#define AE 64
#define MZ 100

typedef unsigned int u32;
typedef unsigned short u16;

typedef __attribute__((ext_vector_type(8))) short bf16x8;
typedef __attribute__((ext_vector_type(4))) float f32x4;

__device__ __forceinline__ bf16x8 as_bf16x8(uint4 v){
  union { uint4 u; bf16x8 b; } x; x.u = v; return x.b;
}

// ---------- bf16 helpers ----------
__device__ __forceinline__ float bf_lo(u32 u){ return __uint_as_float(u << 16); }
__device__ __forceinline__ float bf_hi(u32 u){ return __uint_as_float(u & 0xffff0000u); }
__device__ __forceinline__ u16 f2bf(float f){
  u32 u = __float_as_uint(f);
  u32 r = (u + 0x7fffu + ((u >> 16) & 1u)) >> 16;  // RNE
  return (u16)r;
}
__device__ __forceinline__ u32 pack2(float a, float b){
  return (u32)f2bf(a) | ((u32)f2bf(b) << 16);
}
__device__ __forceinline__ u32 encf(float f){
  u32 u = __float_as_uint(f);
  return (u & 0x80000000u) ? ~u : (u | 0x80000000u);
}
__device__ __forceinline__ float decf(u32 k){
  u32 u = (k & 0x80000000u) ? (k & 0x7fffffffu) : ~k;
  return __uint_as_float(u);
}
__device__ __forceinline__ float sigmoidf_(float x){ return 1.f / (1.f + __expf(-x)); }

// ---------- K0: tables + zero-init + K-major weight transposes for MFMA ----------
__global__ void k0_tables(const float* __restrict__ ae_v, const float* __restrict__ wr1_v,
                          const float* __restrict__ ae_d, const float* __restrict__ wr1_d,
                          const float* __restrict__ wval_v, const float* __restrict__ wproj_v,
                          const float* __restrict__ wval_d, const float* __restrict__ wproj_d,
                          const float* __restrict__ wmsg_v, const float* __restrict__ wmsg_d,
                          const float* __restrict__ wal_v, const float* __restrict__ wal_d,
                          const float* __restrict__ wr2_v, const float* __restrict__ wr2_d,
                          float* __restrict__ radz, float* __restrict__ wpv,
                          u32* __restrict__ mkey, float* __restrict__ den,
                          float* __restrict__ acc, u32* __restrict__ cnt,
                          u32* __restrict__ WtM, u32* __restrict__ WtA,
                          u32* __restrict__ WtR1, u32* __restrict__ WtR2)
{
  int idx = blockIdx.x * 256 + threadIdx.x;
  if (idx < 2 * 2 * MZ * CC) {   // radz[tag][sd][z][c]
    int c = idx & 127;
    int z = (idx >> 7) % MZ;
    int sd = (idx / (128 * MZ)) & 1;
    int tag = idx / (128 * MZ * 2);
    const float* ae = tag ? ae_d : ae_v;
    const float* w  = tag ? wr1_d : wr1_v;
    float s = 0.f;
    for (int a = 0; a < AE; ++a)
      s += ae[z * AE + a] * w[(DR + sd * AE + a) * CC + c];
    radz[idx] = s;
  }
  int i2 = idx - 2 * 2 * MZ * CC;
  if (i2 >= 0 && i2 < 2 * CC * NH) {   // wpv[tag][c][h]
    int h = i2 & 7;
    int c = (i2 >> 3) & 127;
    int tag = i2 >> 10;
    const float* wv = tag ? wval_d : wval_v;
    const float* wp = tag ? wproj_d : wproj_v;
    float s = 0.f;
    for (int q = 0; q < VCD; ++q) s += wv[c * (NH * VCD) + h * VCD + q] * wp[h * VCD + q];
    wpv[i2] = s;
  }
  int i3 = i2 - 2 * CC * NH;
  if (i3 >= 0 && i3 < 2 * NN * NH) mkey[i3] = 0u;
  int i4 = i3 - 2 * NN * NH;
  if (i4 >= 0 && i4 < 2 * NN * NH) den[i4] = 0.f;
  int i5 = i4 - 2 * NN * NH;
  if (i5 >= 0 && i5 < 2 * NN * 3) acc[i5] = 0.f;
  int i6 = i5 - 2 * NN * 3;
  if (i6 >= 0 && i6 < NN) cnt[i6] = 0u;
  int i7 = i6 - NN;
  if (i7 >= 0 && i7 < 4 * 128 * 64) {   // WtM[chunk][col][kp]
    int chunk = i7 >> 13;
    int col = (i7 >> 6) & 127;
    int kp = i7 & 63;
    const float* Wm = (chunk >= 2) ? wmsg_d : wmsg_v;
    int kb = 128 * (chunk & 1);
    WtM[i7] = pack2(Wm[(kb + 2 * kp) * 128 + col], Wm[(kb + 2 * kp + 1) * 128 + col]);
  }
  int i8 = i7 - 4 * 128 * 64;
  if (i8 >= 0 && i8 < 2 * 256 * 64) {   // WtA[tag][col][kp]
    int tag = i8 >> 14;
    int col = (i8 >> 6) & 255;
    int kp = i8 & 63;
    const float* Wa = tag ? wal_d : wal_v;
    WtA[i8] = pack2(Wa[(2 * kp) * 256 + col], Wa[(2 * kp + 1) * 256 + col]);
  }
  int i9 = i8 - 2 * 256 * 64;
  if (i9 >= 0 && i9 < 2 * 128 * 64) {   // WtR1[tag][col][kp]
    int tag = i9 >> 13;
    int col = (i9 >> 6) & 127;
    int kp = i9 & 63;
    const float* W = tag ? wr1_d : wr1_v;
    WtR1[i9] = pack2(W[(2 * kp) * 128 + col], W[(2 * kp + 1) * 128 + col]);
  }
  int i10 = i9 - 2 * 128 * 64;
  if (i10 >= 0 && i10 < 2 * 128 * 64) {   // WtR2[tag][col][kp]
    int tag = i10 >> 13;
    int col = (i10 >> 6) & 127;
    int kp = i10 & 63;
    const float* W = tag ? wr2_d : wr2_v;
    WtR2[i10] = pack2(W[(2 * kp) * 128 + col], W[(2 * kp + 1) * 128 + col]);
  }
}

// ---------- K0b: detect mask storage format ----------
__global__ void k0_flag(const u32* __restrict__ mw, int* __restrict__ flag)
{
  __shared__ int bad;
  if (threadIdx.x == 0) bad = 0;
  __syncthreads();
  int lbad = 0;
  for (int i = threadIdx.x; i < 1248; i += 256)
    if (mw[i] > 1u) lbad = 1;
  if (lbad) bad = 1;
  __syncthreads();
  if (threadIdx.x == 0) *flag = bad;   // 1 => bytes, 0 => int32
}

// ---------- sort: histogram / scan / scatter (counting sort by dst) ----------
__global__ void ks_hist(const int* __restrict__ eidx, u32* __restrict__ cnt)
{
  int idx = blockIdx.x * 256 + threadIdx.x;
  if (idx < NE) atomicAdd(&cnt[eidx[NE + idx]], 1u);
}

__global__ void ks_scan(u32* __restrict__ cnt)   // in-place exclusive prefix, 1 block
{
  __shared__ u32 tsum[256];
  int t = threadIdx.x;
  u32 loc[20];
  u32 s = 0;
  #pragma unroll
  for (int k = 0; k < 20; ++k) {
    int b = t * 20 + k;
    loc[k] = (b < NN) ? cnt[b] : 0u;
    s += loc[k];
  }
  tsum[t] = s;
  __syncthreads();
  for (int off = 1; off < 256; off <<= 1) {
    u32 v = (t >= off) ? tsum[t - off] : 0u;
    __syncthreads();
    tsum[t] += v;
    __syncthreads();
  }
  u32 base = (t == 0) ? 0u : tsum[t - 1];
  #pragma unroll
  for (int k = 0; k < 20; ++k) {
    int b = t * 20 + k;
    if (b < NN) cnt[b] = base;
    base += loc[k];
  }
}

__global__ void ks_scatter(const int* __restrict__ eidx, u32* __restrict__ base,
                           u32* __restrict__ eperm, int* __restrict__ ssrc, int* __restrict__ sdst)
{
  int idx = blockIdx.x * 256 + threadIdx.x;
  if (idx >= NE) return;
  int d = eidx[NE + idx];
  u32 pos = atomicAdd(&base[d], 1u);
  eperm[pos] = (u32)idx;
  ssrc[pos] = eidx[idx];
  sdst[pos] = d;
}

// ---------- K1 (MFMA): P = x @ W_msg halves; 32 rows x 512 cols per block ----------
__global__ __launch_bounds__(256) void k1_nodepre(const float* __restrict__ x,
                                                  const u32* __restrict__ WtM,
                                                  u32* __restrict__ P32)
{
  __shared__ uint4 As4[32 * 17];
  u32* As = (u32*)As4;
  int t = threadIdx.x;
  int row0 = blockIdx.x * 32;
  for (int i = t; i < 32 * 64; i += 256) {
    int r = i >> 6, cp = i & 63;
    int row = row0 + r;
    u32 v = 0u;
    if (row < NN * LL) {
      float2 xv = *(const float2*)(x + (size_t)row * CC + 2 * cp);
      v = pack2(xv.x, xv.y);
    }
    As[r * 68 + cp] = v;
  }
  __syncthreads();
  int w = t >> 6, lane = t & 63;
  int m = lane & 15, kb = lane >> 4;
  int r16 = 16 * (w & 1);
  int cb = 256 * (w >> 1);
  bf16x8 afr[4];
  #pragma unroll
  for (int ks = 0; ks < 4; ++ks)
    afr[ks] = as_bf16x8(*(const uint4*)&As[(r16 + m) * 68 + ks * 16 + kb * 4]);
  int rowbase = row0 + r16;
  for (int ct = 0; ct < 16; ++ct) {
    int col = cb + ct * 16 + m;          // 0..511
    int chunk = col >> 7;
    int cl = col & 127;
    f32x4 accv = {0.f, 0.f, 0.f, 0.f};
    #pragma unroll
    for (int ks = 0; ks < 4; ++ks) {
      bf16x8 bfr = as_bf16x8(*(const uint4*)(WtM + ((size_t)chunk * 128 + cl) * 64 + ks * 16 + kb * 4));
      accv = __builtin_amdgcn_mfma_f32_16x16x32_bf16(afr[ks], bfr, accv, 0, 0, 0);
    }
    #pragma unroll
    for (int reg = 0; reg < 4; ++reg) {
      float v = accv[reg];
      float vv = __shfl_xor(v, 1, 64);
      int row = rowbase + kb * 4 + reg;
      if (((lane & 1) == 0) && row < NN * LL) {
        int n = row / 9, j = row - n * 9;
        P32[((size_t)n * 4 + chunk) * 576 + j * 64 + (cl >> 1)] = pack2(v, vv);
      }
    }
  }
}

// ---------- K23 (MFMA, both tags per block): rad = W_rad2(silu(edist@W_rad1 + radz)) ----------
__global__ __launch_bounds__(256) void k23_rad(const float* __restrict__ edist,
                                               const u32* __restrict__ WtR1,
                                               const u32* __restrict__ WtR2,
                                               const u32* __restrict__ eperm,
                                               const int* __restrict__ ssrc,
                                               const int* __restrict__ sdst,
                                               const int* __restrict__ zn,
                                               const float* __restrict__ radz,
                                               u32* __restrict__ h1rad)
{
  __shared__ uint4 As4[32 * 17];
  __shared__ uint4 Hs4[32 * 17];
  u32* As = (u32*)As4;
  u32* Hs = (u32*)Hs4;
  __shared__ int zsS[32], zdS[32];
  __shared__ u32 epS[32];
  int t = threadIdx.x;
  int e0 = blockIdx.x * 32;
  if (t < 32) {
    int e = e0 + t;
    u32 ep = 0; int s = 0, d = 0;
    if (e < NE) { ep = eperm[e]; s = ssrc[e]; d = sdst[e]; }
    epS[t] = ep; zsS[t] = zn[s]; zdS[t] = zn[d];
  }
  __syncthreads();
  for (int i = t; i < 32 * 64; i += 256) {
    int r = i >> 6, cp = i & 63;
    u32 v = 0u;
    if (e0 + r < NE) {
      float2 xv = *(const float2*)(edist + (size_t)epS[r] * DR + 2 * cp);
      v = pack2(xv.x, xv.y);
    }
    As[r * 68 + cp] = v;
  }
  __syncthreads();
  int w = t >> 6, lane = t & 63;
  int m = lane & 15, kb = lane >> 4;
  int r16 = 16 * (w & 1);
  int cb = 64 * (w >> 1);
  bf16x8 afr0[4];
  #pragma unroll
  for (int ks = 0; ks < 4; ++ks)
    afr0[ks] = as_bf16x8(*(const uint4*)&As[(r16 + m) * 68 + ks * 16 + kb * 4]);
  for (int tag = 0; tag < 2; ++tag) {
    const float* rz_s = radz + tag * 2 * MZ * CC;
    const float* rz_d = rz_s + MZ * CC;
    {  // GEMM1 + radz + silu -> Hs (bf16)
      const u32* B1 = WtR1 + (size_t)tag * 128 * 64;
      #pragma unroll
      for (int ct = 0; ct < 4; ++ct) {
        int col = cb + ct * 16 + m;
        f32x4 accv = {0.f, 0.f, 0.f, 0.f};
        #pragma unroll
        for (int ks = 0; ks < 4; ++ks) {
          bf16x8 bfr = as_bf16x8(*(const uint4*)(B1 + (size_t)col * 64 + ks * 16 + kb * 4));
          accv = __builtin_amdgcn_mfma_f32_16x16x32_bf16(afr0[ks], bfr, accv, 0, 0, 0);
        }
        #pragma unroll
        for (int reg = 0; reg < 4; ++reg) {
          int row = r16 + kb * 4 + reg;
          float v = accv[reg] + rz_s[zsS[row] * CC + col] + rz_d[zdS[row] * CC + col];
          v = v * sigmoidf_(v);
          float vv = __shfl_xor(v, 1, 64);
          if ((m & 1) == 0) Hs[row * 68 + (col >> 1)] = pack2(v, vv);
        }
      }
    }
    __syncthreads();
    {  // GEMM2 -> h1rad (bf16, sorted layout)
      bf16x8 afr[4];
      #pragma unroll
      for (int ks = 0; ks < 4; ++ks)
        afr[ks] = as_bf16x8(*(const uint4*)&Hs[(r16 + m) * 68 + ks * 16 + kb * 4]);
      const u32* B2 = WtR2 + (size_t)tag * 128 * 64;
      #pragma unroll
      for (int ct = 0; ct < 4; ++ct) {
        int col = cb + ct * 16 + m;
        f32x4 accv = {0.f, 0.f, 0.f, 0.f};
        #pragma unroll
        for (int ks = 0; ks < 4; ++ks) {
          bf16x8 bfr = as_bf16x8(*(const uint4*)(B2 + (size_t)col * 64 + ks * 16 + kb * 4));
          accv = __builtin_amdgcn_mfma_f32_16x16x32_bf16(afr[ks], bfr, accv, 0, 0, 0);
        }
        #pragma unroll
        for (int reg = 0; reg < 4; ++reg) {
          int row = r16 + kb * 4 + reg;
          int e = e0 + row;
          float v = accv[reg];
          float vv = __shfl_xor(v, 1, 64);
          if (((m & 1) == 0) && e < NE)
            h1rad[((size_t)tag * NE + e) * 64 + (col >> 1)] = pack2(v, vv);
        }
      }
    }
    __syncthreads();
  }
}

// ---------- KF2: single-gather, Q-factorized {logits+mkey} + {T} ----------
__global__ __launch_bounds__(256) void kF2(const u32* __restrict__ P32,
                                           const float* __restrict__ wig,
                                           const u32* __restrict__ h1rad,
                                           const u32* __restrict__ WtA,
                                           const float* __restrict__ av_v,
                                           const float* __restrict__ av_d,
                                           const float* __restrict__ wpv,
                                           const u32* __restrict__ eperm,
                                           const int* __restrict__ ssrc,
                                           const int* __restrict__ sdst,
                                           float* __restrict__ logits,
                                           u32* __restrict__ mkey,
                                           float* __restrict__ Tbuf)
{
  __shared__ uint4 As4[32 * 17];
  u32* As = (u32*)As4;
  __shared__ float wigS[32][82];
  __shared__ float QS[32][28];      // rows 1..3 of W^T W (27 used)
  __shared__ int es_s[32], ed_s[32];
  __shared__ u32 ep_s[32];
  __shared__ float ltile[32][8];
  __shared__ float wpvS[1024];
  int t = threadIdx.x;
  int tag = blockIdx.y;
  const float* av = tag ? av_d : av_v;
  int i0 = blockIdx.x * 32;
  if (t < 32) {
    int i = i0 + t;
    int s = 0, d = 0; u32 ep = 0;
    if (i < NE) { s = ssrc[i]; d = sdst[i]; ep = eperm[i]; }
    es_s[t] = s; ed_s[t] = d; ep_s[t] = ep;
  }
  for (int q = t; q < 1024; q += 256) wpvS[q] = wpv[tag * 1024 + q];
  __syncthreads();
  for (int q = t; q < 32 * 81; q += 256) {
    int el = q / 81, j = q - el * 81;
    wigS[el][j] = (i0 + el < NE) ? wig[(size_t)ep_s[el] * 81 + j] : 0.f;
  }
  __syncthreads();
  {  // Q build: QS[el][i0q*9+j] = sum_r wig[r,i0q+1]*wig[r,j]
    int el = t >> 3, pp = t & 7;
    #pragma unroll
    for (int k = 0; k < 4; ++k) {
      int q = pp + k * 8;
      if (q < 27) {
        int iq = q / 9, j = q - iq * 9;
        float s = 0.f;
        #pragma unroll
        for (int r = 0; r < 9; ++r)
          s += wigS[el][r * 9 + iq + 1] * wigS[el][r * 9 + j];
        QS[el][q] = s;
      }
    }
  }
  __syncthreads();
  // ---- phase 1: gather + m0 + z (Q-combined) + T, 8 threads/edge ----
  {
    int el = t >> 3, pp = t & 7;     // edge-in-block, channel-pair-quad (owns u32 p=pp*8..pp*8+7)
    int i = i0 + el;
    bool ok = (i < NE);
    float m0[16], z0[16], z1[16], z2[16];
    #pragma unroll
    for (int c = 0; c < 16; ++c) { m0[c] = 0.f; z0[c] = 0.f; z1[c] = 0.f; z2[c] = 0.f; }
    if (ok) {
      const uint4* Ts = (const uint4*)(P32 + ((size_t)es_s[el] * 4 + tag * 2) * 576);
      const uint4* Td = (const uint4*)(P32 + ((size_t)ed_s[el] * 4 + tag * 2 + 1) * 576);
      #pragma unroll
      for (int j = 0; j < 9; ++j) {
        uint4 a0 = Ts[j * 16 + 2 * pp], a1 = Ts[j * 16 + 2 * pp + 1];
        uint4 b0 = Td[j * 16 + 2 * pp], b1 = Td[j * 16 + 2 * pp + 1];
        u32 wa[8] = { a0.x, a0.y, a0.z, a0.w, a1.x, a1.y, a1.z, a1.w };
        u32 wb[8] = { b0.x, b0.y, b0.z, b0.w, b1.x, b1.y, b1.z, b1.w };
        float w0 = wigS[el][j];
        float q0 = QS[el][j], q1 = QS[el][9 + j], q2 = QS[el][18 + j];
        #pragma unroll
        for (int r = 0; r < 8; ++r) {
          float sl = bf_lo(wa[r]) + bf_lo(wb[r]);
          float sh = bf_hi(wa[r]) + bf_hi(wb[r]);
          m0[2 * r]     += w0 * sl;  m0[2 * r + 1] += w0 * sh;
          z0[2 * r]     += q0 * sl;  z0[2 * r + 1] += q0 * sh;
          z1[2 * r]     += q1 * sl;  z1[2 * r + 1] += q1 * sh;
          z2[2 * r]     += q2 * sl;  z2[2 * r + 1] += q2 * sh;
        }
      }
    }
    // rad multiply + gate + As row + T partials
    float tv[3][8];
    #pragma unroll
    for (int i3 = 0; i3 < 3; ++i3)
      #pragma unroll
      for (int h = 0; h < 8; ++h) tv[i3][h] = 0.f;
    {
      uint4 r0u = make_uint4(0,0,0,0), r1u = make_uint4(0,0,0,0);
      if (ok) {
        const uint4* Rp = (const uint4*)(h1rad + ((size_t)tag * NE + i) * 64);
        r0u = Rp[2 * pp]; r1u = Rp[2 * pp + 1];
      }
      u32 wr[8] = { r0u.x, r0u.y, r0u.z, r0u.w, r1u.x, r1u.y, r1u.z, r1u.w };
      #pragma unroll
      for (int r = 0; r < 8; ++r) {
        float rl = bf_lo(wr[r]), rh = bf_hi(wr[r]);
        int cl = 2 * r, ch = 2 * r + 1;
        m0[cl] *= rl; m0[ch] *= rh;
        As[el * 68 + pp * 8 + r] = pack2(m0[cl], m0[ch]);
        float fl = rl * sigmoidf_(m0[cl]);
        float fh = rh * sigmoidf_(m0[ch]);
        float v0l = z0[cl] * fl, v0h = z0[ch] * fh;
        float v1l = z1[cl] * fl, v1h = z1[ch] * fh;
        float v2l = z2[cl] * fl, v2h = z2[ch] * fh;
        int c2 = (pp * 8 + r) * 2;      // channel index of low half
        #pragma unroll
        for (int h = 0; h < 8; ++h) {
          float wl = wpvS[c2 * 8 + h], wh = wpvS[(c2 + 1) * 8 + h];
          tv[0][h] += v0l * wl + v0h * wh;
          tv[1][h] += v1l * wl + v1h * wh;
          tv[2][h] += v2l * wl + v2h * wh;
        }
      }
    }
    // reduce over the edge's 8 threads (consecutive lanes)
    #pragma unroll
    for (int off = 1; off <= 4; off <<= 1)
      #pragma unroll
      for (int i3 = 0; i3 < 3; ++i3)
        #pragma unroll
        for (int h = 0; h < 8; ++h)
          tv[i3][h] += __shfl_xor(tv[i3][h], off, 64);
    if (pp == 0 && ok) {
      float* Tp = Tbuf + ((size_t)tag * NE + i) * 24;
      #pragma unroll
      for (int h = 0; h < 8; ++h) {
        Tp[h * 3 + 0] = tv[0][h];
        Tp[h * 3 + 1] = tv[1][h];
        Tp[h * 3 + 2] = tv[2][h];
      }
    }
  }
  __syncthreads();
  // ---- phase 2: MFMA logits C(32x256) = A(32x128) @ WtA ----
  {
    int w = t >> 6, lane = t & 63;
    int m = lane & 15, kb = lane >> 4;
    int r16 = 16 * (w & 1);
    int cb = 128 * (w >> 1);
    bf16x8 afr[4];
    #pragma unroll
    for (int ks = 0; ks < 4; ++ks)
      afr[ks] = as_bf16x8(*(const uint4*)&As[(r16 + m) * 68 + ks * 16 + kb * 4]);
    const u32* WA = WtA + (size_t)tag * 256 * 64;
    float psum[4][4];
    #pragma unroll
    for (int a = 0; a < 4; ++a)
      #pragma unroll
      for (int b = 0; b < 4; ++b) psum[a][b] = 0.f;
    #pragma unroll
    for (int ct = 0; ct < 8; ++ct) {
      int col = cb + ct * 16 + m;
      f32x4 accv = {0.f, 0.f, 0.f, 0.f};
      #pragma unroll
      for (int ks = 0; ks < 4; ++ks) {
        bf16x8 bfr = as_bf16x8(*(const uint4*)(WA + (size_t)col * 64 + ks * 16 + kb * 4));
        accv = __builtin_amdgcn_mfma_f32_16x16x32_bf16(afr[ks], bfr, accv, 0, 0, 0);
      }
      int hl = ct >> 1;
      float avv = av[(4 * (w >> 1) + hl) * 32 + (ct & 1) * 16 + m];
      #pragma unroll
      for (int reg = 0; reg < 4; ++reg) {
        float aa = accv[reg];
        aa = (aa >= 0.f) ? aa : 0.2f * aa;    // leaky_relu 0.2
        psum[hl][reg] += aa * avv;
      }
    }
    #pragma unroll
    for (int hl = 0; hl < 4; ++hl) {
      #pragma unroll
      for (int reg = 0; reg < 4; ++reg) {
        float v = psum[hl][reg];
        v += __shfl_xor(v, 1, 64);
        v += __shfl_xor(v, 2, 64);
        v += __shfl_xor(v, 4, 64);
        v += __shfl_xor(v, 8, 64);
        if (m == 0) ltile[r16 + kb * 4 + reg][4 * (w >> 1) + hl] = v;
      }
    }
  }
  __syncthreads();
  {
    int el = t >> 3, hh = t & 7;
    int i = i0 + el;
    if (i < NE) {
      float lg = ltile[el][hh];
      logits[((size_t)tag * NE + i) * NH + hh] = lg;
      atomicMax(&mkey[tag * NN * NH + ed_s[el] * NH + hh], encf(lg));
    }
  }
}

// ---------- K5: ex = exp(logit - m[dst]); den = segment_sum (sorted order) ----------
__global__ void k5_ex(const float* __restrict__ logits, const u32* __restrict__ mkey,
                      const int* __restrict__ sdst, float* __restrict__ ex, float* __restrict__ den)
{
  int idx = blockIdx.x * 256 + threadIdx.x;
  if (idx >= 2 * NE * NH) return;
  int h = idx & 7;
  int e = (idx >> 3) % NE;
  int tag = idx / (NE * NH);
  int d = sdst[e];
  float m = decf(mkey[tag * NN * NH + d * NH + h]);
  float v = __expf(logits[idx] - m);
  ex[idx] = v;
  atomicAdd(&den[tag * NN * NH + d * NH + h], v);
}

// ---------- K6s: out contribution = sum_h attn * T, no P traffic ----------
__global__ void k6_scatter(const float* __restrict__ ex, const float* __restrict__ den,
                           const float* __restrict__ Tbuf, const int* __restrict__ sdst,
                           float* __restrict__ acc)
{
  int idx = blockIdx.x * 256 + threadIdx.x;
  if (idx >= 2 * NE) return;
  int tag = idx / NE;
  int e = idx - tag * NE;
  int d = sdst[e];
  const float* Tp = Tbuf + ((size_t)tag * NE + e) * 24;
  float y0 = 0.f, y1 = 0.f, y2 = 0.f;
  #pragma unroll
  for (int h = 0; h < 8; ++h) {
    float at = ex[((size_t)tag * NE + e) * 8 + h]
             / (den[tag * NN * NH + d * NH + h] + 1e-9f);
    y0 += at * Tp[h * 3 + 0];
    y1 += at * Tp[h * 3 + 1];
    y2 += at * Tp[h * 3 + 2];
  }
  atomicAdd(&acc[tag * NN * 3 + d * 3 + 0], y0);
  atomicAdd(&acc[tag * NN * 3 + d * 3 + 1], y1);
  atomicAdd(&acc[tag * NN * 3 + d * 3 + 2], y2);
}

// ---------- K7: masked select, f32 out ----------
__global__ void k7_out(const float* __restrict__ acc, const void* __restrict__ mask,
                       const int* __restrict__ flag, float* __restrict__ out)
{
  int idx = blockIdx.x * 256 + threadIdx.x;
  if (idx >= NN * 3) return;
  int n = idx / 3;
  bool msk;
  if (*flag) msk = ((const unsigned char*)mask)[n] != 0;
  else       msk = ((const int*)mask)[n] != 0;
  out[idx] = msk ? acc[NN * 3 + idx] : acc[idx];
}

extern "C" void kernel_launch(void* const* d_in, const int* in_sizes, int n_in,
                              void* d_out, int out_size, void* d_ws, size_t ws_size,
                              hipStream_t stream)
{
  (void)hipGetLastError();   // clear sticky error state

  bool setup_order = (n_in >= 22) && (in_sizes[3] == NN) && (in_sizes[4] == 2 * NE);
  const float *x, *edist, *wig;
  const int *zn, *eidx;
  const void *mask;
  const float *ae_v, *wr1_v, *wr2_v, *wmsg_v, *wal_v, *av_v, *wval_v, *wproj_v;
  const float *ae_d, *wr1_d, *wr2_d, *wmsg_d, *wal_d, *av_d, *wval_d, *wproj_d;
  x     = (const float*)d_in[0];
  edist = (const float*)d_in[1];
  wig   = (const float*)d_in[2];
  if (setup_order) {
    zn      = (const int*)d_in[3];
    eidx    = (const int*)d_in[4];
    mask    = d_in[5];
    ae_v    = (const float*)d_in[6];   wr1_v  = (const float*)d_in[7];
    wr2_v   = (const float*)d_in[8];   wmsg_v = (const float*)d_in[9];
    wal_v   = (const float*)d_in[10];  av_v   = (const float*)d_in[11];
    wval_v  = (const float*)d_in[12];  wproj_v= (const float*)d_in[13];
    ae_d    = (const float*)d_in[14];  wr1_d  = (const float*)d_in[15];
    wr2_d   = (const float*)d_in[16];  wmsg_d = (const float*)d_in[17];
    wal_d   = (const float*)d_in[18];  av_d   = (const float*)d_in[19];
    wval_d  = (const float*)d_in[20];  wproj_d= (const float*)d_in[21];
  } else {
    ae_v    = (const float*)d_in[3];   wr1_v  = (const float*)d_in[4];
    wr2_v   = (const float*)d_in[5];   wmsg_v = (const float*)d_in[6];
    wal_v   = (const float*)d_in[7];   av_v   = (const float*)d_in[8];
    wval_v  = (const float*)d_in[9];   wproj_v= (const float*)d_in[10];
    ae_d    = (const float*)d_in[11];  wr1_d  = (const float*)d_in[12];
    wr2_d   = (const float*)d_in[13];  wmsg_d = (const float*)d_in[14];
    wal_d   = (const float*)d_in[15];  av_d   = (const float*)d_in[16];
    wval_d  = (const float*)d_in[17];  wproj_d= (const float*)d_in[18];
    zn      = (const int*)d_in[19];
    eidx    = (const int*)d_in[20];
    mask    = d_in[21];
  }

  // ---- workspace layout (bytes) ----
  const size_t OFF_P    = 0;              // 46,080,000
  const size_t OFF_H1   = 46080000;       // 25,600,000
  const size_t OFF_LOG  = 71680000;       //  3,200,000
  const size_t OFF_EX   = 74880000;       //  3,200,000
  const size_t OFF_T    = 78080000;       //  9,600,000 (2*NE*24 f32)
  const size_t OFF_MK   = 87680000;       //    320,000
  const size_t OFF_DEN  = 88000000;       //    320,000
  const size_t OFF_ACC  = 88320000;       //    120,000
  const size_t OFF_RADZ = 88440000;       //    204,800
  const size_t OFF_WPV  = 88644800;       //      8,192
  const size_t OFF_FLAG = 88652992;       //         64
  const size_t OFF_CNT  = 88653056;       //     20,000
  const size_t OFF_PERM = 88673056;       //    200,000
  const size_t OFF_SSRC = 88873056;       //    200,000
  const size_t OFF_SDST = 89073056;       //    200,000
  const size_t OFF_WTM  = 89273056;       //    131,072
  const size_t OFF_WTA  = 89404128;       //    131,072
  const size_t OFF_WTR1 = 89535200;       //     65,536
  const size_t OFF_WTR2 = 89600736;       //     65,536
  const size_t NEEDED   = 89666272;

  const size_t out_bytes = (size_t)out_size * sizeof(float);

  if (d_ws == nullptr || ws_size < NEEDED) {
    hipMemsetAsync(d_out, 0x66, out_bytes, stream);   // ws-too-small signature
    return;
  }

  char* ws = (char*)d_ws;
  u32*   P32    = (u32*)(ws + OFF_P);
  u32*   h1rad  = (u32*)(ws + OFF_H1);
  float* logits = (float*)(ws + OFF_LOG);
  float* ex     = (float*)(ws + OFF_EX);
  float* Tbuf   = (float*)(ws + OFF_T);
  u32*   mkey   = (u32*)(ws + OFF_MK);
  float* den    = (float*)(ws + OFF_DEN);
  float* acc    = (float*)(ws + OFF_ACC);
  float* radz   = (float*)(ws + OFF_RADZ);
  float* wpv    = (float*)(ws + OFF_WPV);
  int*   flag   = (int*)(ws + OFF_FLAG);
  u32*   cnt    = (u32*)(ws + OFF_CNT);
  u32*   eperm  = (u32*)(ws + OFF_PERM);
  int*   ssrc   = (int*)(ws + OFF_SSRC);
  int*   sdst   = (int*)(ws + OFF_SDST);
  u32*   WtM    = (u32*)(ws + OFF_WTM);
  u32*   WtA    = (u32*)(ws + OFF_WTA);
  u32*   WtR1   = (u32*)(ws + OFF_WTR1);
  u32*   WtR2   = (u32*)(ws + OFF_WTR2);

  k0_tables<<<1354, 256, 0, stream>>>(ae_v, wr1_v, ae_d, wr1_d,
                                      wval_v, wproj_v, wval_d, wproj_d,
                                      wmsg_v, wmsg_d, wal_v, wal_d,
                                      wr2_v, wr2_d,
                                      radz, wpv, mkey, den, acc, cnt,
                                      WtM, WtA, WtR1, WtR2);
  k0_flag<<<1, 256, 0, stream>>>((const u32*)mask, flag);
  ks_hist<<<196, 256, 0, stream>>>(eidx, cnt);
  ks_scan<<<1, 256, 0, stream>>>(cnt);
  ks_scatter<<<196, 256, 0, stream>>>(eidx, cnt, eperm, ssrc, sdst);
  k1_nodepre<<<1407, 256, 0, stream>>>(x, WtM, P32);
  k23_rad<<<1563, 256, 0, stream>>>(edist, WtR1, WtR2, eperm, ssrc, sdst,
                                    zn, radz, h1rad);
  kF2<<<dim3(1563, 2), 256, 0, stream>>>(P32, wig, h1rad, WtA, av_v, av_d, wpv,
                                         eperm, ssrc, sdst, logits, mkey, Tbuf);
  k5_ex<<<3125, 256, 0, stream>>>(logits, mkey, sdst, ex, den);
  k6_scatter<<<391, 256, 0, stream>>>(ex, den, Tbuf, sdst, acc);
  k7_out<<<59, 256, 0, stream>>>(acc, mask, flag, (float*)d_out);

  if (hipGetLastError() != hipSuccess) {
    hipMemsetAsync(d_out, 0x77, out_bytes, stream);   // launch-failure signature
  }
}

// Round 10
// 530.687 us; speedup vs baseline: 1.0948x; 1.0518x over previous
//
#include <hip/hip_runtime.h>

#define NN 5000
#define NE 50000
#define LL 9
#define CC 128
#define NH 8
#define VCD 16
#define DR 128
#define AE 64
#define MZ 100

typedef unsigned int u32;
typedef unsigned short u16;

typedef __attribute__((ext_vector_type(8))) short bf16x8;
typedef __attribute__((ext_vector_type(4))) float f32x4;

__device__ __forceinline__ bf16x8 as_bf16x8(uint4 v){
  union { uint4 u; bf16x8 b; } x; x.u = v; return x.b;
}

// ---------- bf16 helpers ----------
__device__ __forceinline__ float bf_lo(u32 u){ return __uint_as_float(u << 16); }
__device__ __forceinline__ float bf_hi(u32 u){ return __uint_as_float(u & 0xffff0000u); }
__device__ __forceinline__ u16 f2bf(float f){
  u32 u = __float_as_uint(f);
  u32 r = (u + 0x7fffu + ((u >> 16) & 1u)) >> 16;  // RNE
  return (u16)r;
}
__device__ __forceinline__ u32 pack2(float a, float b){
  return (u32)f2bf(a) | ((u32)f2bf(b) << 16);
}
__device__ __forceinline__ u32 encf(float f){
  u32 u = __float_as_uint(f);
  return (u & 0x80000000u) ? ~u : (u | 0x80000000u);
}
__device__ __forceinline__ float decf(u32 k){
  u32 u = (k & 0x80000000u) ? (k & 0x7fffffffu) : ~k;
  return __uint_as_float(u);
}
__device__ __forceinline__ float sigmoidf_(float x){ return 1.f / (1.f + __expf(-x)); }

// ---------- K0: tables + zero-init + K-major weight transposes for MFMA ----------
__global__ void k0_tables(const float* __restrict__ ae_v, const float* __restrict__ wr1_v,
                          const float* __restrict__ ae_d, const float* __restrict__ wr1_d,
                          const float* __restrict__ wval_v, const float* __restrict__ wproj_v,
                          const float* __restrict__ wval_d, const float* __restrict__ wproj_d,
                          const float* __restrict__ wmsg_v, const float* __restrict__ wmsg_d,
                          const float* __restrict__ wal_v, const float* __restrict__ wal_d,
                          const float* __restrict__ wr2_v, const float* __restrict__ wr2_d,
                          float* __restrict__ radz, float* __restrict__ wpv,
                          u32* __restrict__ mkey, float* __restrict__ den,
                          float* __restrict__ acc, u32* __restrict__ cnt,
                          u32* __restrict__ WtM, u32* __restrict__ WtA,
                          u32* __restrict__ WtR1, u32* __restrict__ WtR2)
{
  int idx = blockIdx.x * 256 + threadIdx.x;
  if (idx < 2 * 2 * MZ * CC) {   // radz[tag][sd][z][c]
    int c = idx & 127;
    int z = (idx >> 7) % MZ;
    int sd = (idx / (128 * MZ)) & 1;
    int tag = idx / (128 * MZ * 2);
    const float* ae = tag ? ae_d : ae_v;
    const float* w  = tag ? wr1_d : wr1_v;
    float s = 0.f;
    for (int a = 0; a < AE; ++a)
      s += ae[z * AE + a] * w[(DR + sd * AE + a) * CC + c];
    radz[idx] = s;
  }
  int i2 = idx - 2 * 2 * MZ * CC;
  if (i2 >= 0 && i2 < 2 * CC * NH) {   // wpv[tag][c][h]
    int h = i2 & 7;
    int c = (i2 >> 3) & 127;
    int tag = i2 >> 10;
    const float* wv = tag ? wval_d : wval_v;
    const float* wp = tag ? wproj_d : wproj_v;
    float s = 0.f;
    for (int q = 0; q < VCD; ++q) s += wv[c * (NH * VCD) + h * VCD + q] * wp[h * VCD + q];
    wpv[i2] = s;
  }
  int i3 = i2 - 2 * CC * NH;
  if (i3 >= 0 && i3 < 2 * NN * NH) mkey[i3] = 0u;
  int i4 = i3 - 2 * NN * NH;
  if (i4 >= 0 && i4 < 2 * NN * NH) den[i4] = 0.f;
  int i5 = i4 - 2 * NN * NH;
  if (i5 >= 0 && i5 < 2 * NN * 3) acc[i5] = 0.f;
  int i6 = i5 - 2 * NN * 3;
  if (i6 >= 0 && i6 < NN) cnt[i6] = 0u;
  int i7 = i6 - NN;
  if (i7 >= 0 && i7 < 4 * 128 * 64) {   // WtM[chunk][col][kp]
    int chunk = i7 >> 13;
    int col = (i7 >> 6) & 127;
    int kp = i7 & 63;
    const float* Wm = (chunk >= 2) ? wmsg_d : wmsg_v;
    int kb = 128 * (chunk & 1);
    WtM[i7] = pack2(Wm[(kb + 2 * kp) * 128 + col], Wm[(kb + 2 * kp + 1) * 128 + col]);
  }
  int i8 = i7 - 4 * 128 * 64;
  if (i8 >= 0 && i8 < 2 * 256 * 64) {   // WtA[tag][col][kp]
    int tag = i8 >> 14;
    int col = (i8 >> 6) & 255;
    int kp = i8 & 63;
    const float* Wa = tag ? wal_d : wal_v;
    WtA[i8] = pack2(Wa[(2 * kp) * 256 + col], Wa[(2 * kp + 1) * 256 + col]);
  }
  int i9 = i8 - 2 * 256 * 64;
  if (i9 >= 0 && i9 < 2 * 128 * 64) {   // WtR1[tag][col][kp]
    int tag = i9 >> 13;
    int col = (i9 >> 6) & 127;
    int kp = i9 & 63;
    const float* W = tag ? wr1_d : wr1_v;
    WtR1[i9] = pack2(W[(2 * kp) * 128 + col], W[(2 * kp + 1) * 128 + col]);
  }
  int i10 = i9 - 2 * 128 * 64;
  if (i10 >= 0 && i10 < 2 * 128 * 64) {   // WtR2[tag][col][kp]
    int tag = i10 >> 13;
    int col = (i10 >> 6) & 127;
    int kp = i10 & 63;
    const float* W = tag ? wr2_d : wr2_v;
    WtR2[i10] = pack2(W[(2 * kp) * 128 + col], W[(2 * kp + 1) * 128 + col]);
  }
}

// ---------- K0b: detect mask storage format ----------
__global__ void k0_flag(const u32* __restrict__ mw, int* __restrict__ flag)
{
  __shared__ int bad;
  if (threadIdx.x == 0) bad = 0;
  __syncthreads();
  int lbad = 0;
  for (int i = threadIdx.x; i < 1248; i += 256)
    if (mw[i] > 1u) lbad = 1;
  if (lbad) bad = 1;
  __syncthreads();
  if (threadIdx.x == 0) *flag = bad;   // 1 => bytes, 0 => int32
}

// ---------- sort: histogram / scan / scatter (counting sort by dst) ----------
__global__ void ks_hist(const int* __restrict__ eidx, u32* __restrict__ cnt)
{
  int idx = blockIdx.x * 256 + threadIdx.x;
  if (idx < NE) atomicAdd(&cnt[eidx[NE + idx]], 1u);
}

__global__ void ks_scan(u32* __restrict__ cnt)   // in-place exclusive prefix, 1 block
{
  __shared__ u32 tsum[256];
  int t = threadIdx.x;
  u32 loc[20];
  u32 s = 0;
  #pragma unroll
  for (int k = 0; k < 20; ++k) {
    int b = t * 20 + k;
    loc[k] = (b < NN) ? cnt[b] : 0u;
    s += loc[k];
  }
  tsum[t] = s;
  __syncthreads();
  for (int off = 1; off < 256; off <<= 1) {
    u32 v = (t >= off) ? tsum[t - off] : 0u;
    __syncthreads();
    tsum[t] += v;
    __syncthreads();
  }
  u32 base = (t == 0) ? 0u : tsum[t - 1];
  #pragma unroll
  for (int k = 0; k < 20; ++k) {
    int b = t * 20 + k;
    if (b < NN) cnt[b] = base;
    base += loc[k];
  }
}

__global__ void ks_scatter(const int* __restrict__ eidx, u32* __restrict__ base,
                           u32* __restrict__ eperm, int* __restrict__ ssrc, int* __restrict__ sdst)
{
  int idx = blockIdx.x * 256 + threadIdx.x;
  if (idx >= NE) return;
  int d = eidx[NE + idx];
  u32 pos = atomicAdd(&base[d], 1u);
  eperm[pos] = (u32)idx;
  ssrc[pos] = eidx[idx];
  sdst[pos] = d;
}

// ---------- K1 (MFMA): P = x @ W_msg halves; 32 rows x 512 cols per block ----------
__global__ __launch_bounds__(256) void k1_nodepre(const float* __restrict__ x,
                                                  const u32* __restrict__ WtM,
                                                  u32* __restrict__ P32)
{
  __shared__ uint4 As4[32 * 17];
  u32* As = (u32*)As4;
  int t = threadIdx.x;
  int row0 = blockIdx.x * 32;
  for (int i = t; i < 32 * 64; i += 256) {
    int r = i >> 6, cp = i & 63;
    int row = row0 + r;
    u32 v = 0u;
    if (row < NN * LL) {
      float2 xv = *(const float2*)(x + (size_t)row * CC + 2 * cp);
      v = pack2(xv.x, xv.y);
    }
    As[r * 68 + cp] = v;
  }
  __syncthreads();
  int w = t >> 6, lane = t & 63;
  int m = lane & 15, kb = lane >> 4;
  int r16 = 16 * (w & 1);
  int cb = 256 * (w >> 1);
  bf16x8 afr[4];
  #pragma unroll
  for (int ks = 0; ks < 4; ++ks)
    afr[ks] = as_bf16x8(*(const uint4*)&As[(r16 + m) * 68 + ks * 16 + kb * 4]);
  int rowbase = row0 + r16;
  for (int ct = 0; ct < 16; ++ct) {
    int col = cb + ct * 16 + m;          // 0..511
    int chunk = col >> 7;
    int cl = col & 127;
    f32x4 accv = {0.f, 0.f, 0.f, 0.f};
    #pragma unroll
    for (int ks = 0; ks < 4; ++ks) {
      bf16x8 bfr = as_bf16x8(*(const uint4*)(WtM + ((size_t)chunk * 128 + cl) * 64 + ks * 16 + kb * 4));
      accv = __builtin_amdgcn_mfma_f32_16x16x32_bf16(afr[ks], bfr, accv, 0, 0, 0);
    }
    #pragma unroll
    for (int reg = 0; reg < 4; ++reg) {
      float v = accv[reg];
      float vv = __shfl_xor(v, 1, 64);
      int row = rowbase + kb * 4 + reg;
      if (((lane & 1) == 0) && row < NN * LL) {
        int n = row / 9, j = row - n * 9;
        P32[((size_t)n * 4 + chunk) * 576 + j * 64 + (cl >> 1)] = pack2(v, vv);
      }
    }
  }
}

// ---------- K23 (MFMA, both tags per block): rad = W_rad2(silu(edist@W_rad1 + radz)) ----------
__global__ __launch_bounds__(256) void k23_rad(const float* __restrict__ edist,
                                               const u32* __restrict__ WtR1,
                                               const u32* __restrict__ WtR2,
                                               const u32* __restrict__ eperm,
                                               const int* __restrict__ ssrc,
                                               const int* __restrict__ sdst,
                                               const int* __restrict__ zn,
                                               const float* __restrict__ radz,
                                               u32* __restrict__ h1rad)
{
  __shared__ uint4 As4[32 * 17];
  __shared__ uint4 Hs4[32 * 17];
  u32* As = (u32*)As4;
  u32* Hs = (u32*)Hs4;
  __shared__ int zsS[32], zdS[32];
  __shared__ u32 epS[32];
  int t = threadIdx.x;
  int e0 = blockIdx.x * 32;
  if (t < 32) {
    int e = e0 + t;
    u32 ep = 0; int s = 0, d = 0;
    if (e < NE) { ep = eperm[e]; s = ssrc[e]; d = sdst[e]; }
    epS[t] = ep; zsS[t] = zn[s]; zdS[t] = zn[d];
  }
  __syncthreads();
  for (int i = t; i < 32 * 64; i += 256) {
    int r = i >> 6, cp = i & 63;
    u32 v = 0u;
    if (e0 + r < NE) {
      float2 xv = *(const float2*)(edist + (size_t)epS[r] * DR + 2 * cp);
      v = pack2(xv.x, xv.y);
    }
    As[r * 68 + cp] = v;
  }
  __syncthreads();
  int w = t >> 6, lane = t & 63;
  int m = lane & 15, kb = lane >> 4;
  int r16 = 16 * (w & 1);
  int cb = 64 * (w >> 1);
  bf16x8 afr0[4];
  #pragma unroll
  for (int ks = 0; ks < 4; ++ks)
    afr0[ks] = as_bf16x8(*(const uint4*)&As[(r16 + m) * 68 + ks * 16 + kb * 4]);
  for (int tag = 0; tag < 2; ++tag) {
    const float* rz_s = radz + tag * 2 * MZ * CC;
    const float* rz_d = rz_s + MZ * CC;
    {  // GEMM1 + radz + silu -> Hs (bf16)
      const u32* B1 = WtR1 + (size_t)tag * 128 * 64;
      #pragma unroll
      for (int ct = 0; ct < 4; ++ct) {
        int col = cb + ct * 16 + m;
        f32x4 accv = {0.f, 0.f, 0.f, 0.f};
        #pragma unroll
        for (int ks = 0; ks < 4; ++ks) {
          bf16x8 bfr = as_bf16x8(*(const uint4*)(B1 + (size_t)col * 64 + ks * 16 + kb * 4));
          accv = __builtin_amdgcn_mfma_f32_16x16x32_bf16(afr0[ks], bfr, accv, 0, 0, 0);
        }
        #pragma unroll
        for (int reg = 0; reg < 4; ++reg) {
          int row = r16 + kb * 4 + reg;
          float v = accv[reg] + rz_s[zsS[row] * CC + col] + rz_d[zdS[row] * CC + col];
          v = v * sigmoidf_(v);
          float vv = __shfl_xor(v, 1, 64);
          if ((m & 1) == 0) Hs[row * 68 + (col >> 1)] = pack2(v, vv);
        }
      }
    }
    __syncthreads();
    {  // GEMM2 -> h1rad (bf16, sorted layout)
      bf16x8 afr[4];
      #pragma unroll
      for (int ks = 0; ks < 4; ++ks)
        afr[ks] = as_bf16x8(*(const uint4*)&Hs[(r16 + m) * 68 + ks * 16 + kb * 4]);
      const u32* B2 = WtR2 + (size_t)tag * 128 * 64;
      #pragma unroll
      for (int ct = 0; ct < 4; ++ct) {
        int col = cb + ct * 16 + m;
        f32x4 accv = {0.f, 0.f, 0.f, 0.f};
        #pragma unroll
        for (int ks = 0; ks < 4; ++ks) {
          bf16x8 bfr = as_bf16x8(*(const uint4*)(B2 + (size_t)col * 64 + ks * 16 + kb * 4));
          accv = __builtin_amdgcn_mfma_f32_16x16x32_bf16(afr[ks], bfr, accv, 0, 0, 0);
        }
        #pragma unroll
        for (int reg = 0; reg < 4; ++reg) {
          int row = r16 + kb * 4 + reg;
          int e = e0 + row;
          float v = accv[reg];
          float vv = __shfl_xor(v, 1, 64);
          if (((m & 1) == 0) && e < NE)
            h1rad[((size_t)tag * NE + e) * 64 + (col >> 1)] = pack2(v, vv);
        }
      }
    }
    __syncthreads();
  }
}

// ---------- K4 (MFMA): logits + segment max; 16 thr/edge A-build, 4 waves/SIMD ----------
__global__ __launch_bounds__(256, 4) void k4_logits(const u32* __restrict__ P32,
                                                    const float* __restrict__ wig,
                                                    const u32* __restrict__ h1rad,
                                                    const u32* __restrict__ WtA,
                                                    const float* __restrict__ av_v,
                                                    const float* __restrict__ av_d,
                                                    const u32* __restrict__ eperm,
                                                    const int* __restrict__ ssrc,
                                                    const int* __restrict__ sdst,
                                                    float* __restrict__ logits,
                                                    u32* __restrict__ mkey)
{
  __shared__ uint4 As4[32 * 17];
  u32* As = (u32*)As4;
  __shared__ float wig0s[32][9];
  __shared__ int es_s[32], ed_s[32];
  __shared__ u32 ep_s[32];
  __shared__ float ltile[32][8];
  int t = threadIdx.x;
  int tag = blockIdx.y;
  const float* av = tag ? av_d : av_v;      // (8,32)
  int i0 = blockIdx.x * 32;
  if (t < 32) {
    int i = i0 + t;
    int s = 0, d = 0; u32 ep = 0;
    if (i < NE) { s = ssrc[i]; d = sdst[i]; ep = eperm[i]; }
    es_s[t] = s; ed_s[t] = d; ep_s[t] = ep;
  }
  __syncthreads();
  for (int q = t; q < 32 * 9; q += 256) {
    int el = q / 9, j = q % 9;
    wig0s[el][j] = (i0 + el < NE) ? wig[(size_t)ep_s[el] * 81 + j] : 0.f;
  }
  __syncthreads();
  // ---- phase 1: A build, 16 threads/edge x 2 passes (low reg pressure) ----
  #pragma unroll
  for (int pass = 0; pass < 2; ++pass) {
    int el = (t >> 4) + pass * 16;
    int pp = t & 15;                    // owns u32 indices pp*4 .. pp*4+3 (8 channels)
    int i = i0 + el;
    bool ok = (i < NE);
    float m0[8];
    #pragma unroll
    for (int c = 0; c < 8; ++c) m0[c] = 0.f;
    if (ok) {
      const uint4* Ts = (const uint4*)(P32 + ((size_t)es_s[el] * 4 + tag * 2) * 576);
      const uint4* Td = (const uint4*)(P32 + ((size_t)ed_s[el] * 4 + tag * 2 + 1) * 576);
      #pragma unroll
      for (int j = 0; j < 9; ++j) {
        float w = wig0s[el][j];
        uint4 a = Ts[j * 16 + pp];
        uint4 b = Td[j * 16 + pp];
        m0[0] += w * (bf_lo(a.x) + bf_lo(b.x));
        m0[1] += w * (bf_hi(a.x) + bf_hi(b.x));
        m0[2] += w * (bf_lo(a.y) + bf_lo(b.y));
        m0[3] += w * (bf_hi(a.y) + bf_hi(b.y));
        m0[4] += w * (bf_lo(a.z) + bf_lo(b.z));
        m0[5] += w * (bf_hi(a.z) + bf_hi(b.z));
        m0[6] += w * (bf_lo(a.w) + bf_lo(b.w));
        m0[7] += w * (bf_hi(a.w) + bf_hi(b.w));
      }
      uint4 rr = ((const uint4*)(h1rad + ((size_t)tag * NE + i) * 64))[pp];
      m0[0] *= bf_lo(rr.x); m0[1] *= bf_hi(rr.x);
      m0[2] *= bf_lo(rr.y); m0[3] *= bf_hi(rr.y);
      m0[4] *= bf_lo(rr.z); m0[5] *= bf_hi(rr.z);
      m0[6] *= bf_lo(rr.w); m0[7] *= bf_hi(rr.w);
    }
    uint4 v4;
    v4.x = pack2(m0[0], m0[1]);
    v4.y = pack2(m0[2], m0[3]);
    v4.z = pack2(m0[4], m0[5]);
    v4.w = pack2(m0[6], m0[7]);
    *(uint4*)&As[el * 68 + pp * 4] = v4;
  }
  __syncthreads();
  // ---- phase 2: MFMA logits C(32x256) = A(32x128) @ WtA ----
  {
    int w = t >> 6, lane = t & 63;
    int m = lane & 15, kb = lane >> 4;
    int r16 = 16 * (w & 1);
    int cb = 128 * (w >> 1);
    bf16x8 afr[4];
    #pragma unroll
    for (int ks = 0; ks < 4; ++ks)
      afr[ks] = as_bf16x8(*(const uint4*)&As[(r16 + m) * 68 + ks * 16 + kb * 4]);
    const u32* WA = WtA + (size_t)tag * 256 * 64;
    float psum[4][4];
    #pragma unroll
    for (int a = 0; a < 4; ++a)
      #pragma unroll
      for (int b = 0; b < 4; ++b) psum[a][b] = 0.f;
    #pragma unroll
    for (int ct = 0; ct < 8; ++ct) {
      int col = cb + ct * 16 + m;
      f32x4 accv = {0.f, 0.f, 0.f, 0.f};
      #pragma unroll
      for (int ks = 0; ks < 4; ++ks) {
        bf16x8 bfr = as_bf16x8(*(const uint4*)(WA + (size_t)col * 64 + ks * 16 + kb * 4));
        accv = __builtin_amdgcn_mfma_f32_16x16x32_bf16(afr[ks], bfr, accv, 0, 0, 0);
      }
      int hl = ct >> 1;
      float avv = av[(4 * (w >> 1) + hl) * 32 + (ct & 1) * 16 + m];
      #pragma unroll
      for (int reg = 0; reg < 4; ++reg) {
        float aa = accv[reg];
        aa = (aa >= 0.f) ? aa : 0.2f * aa;    // leaky_relu 0.2
        psum[hl][reg] += aa * avv;
      }
    }
    #pragma unroll
    for (int hl = 0; hl < 4; ++hl) {
      #pragma unroll
      for (int reg = 0; reg < 4; ++reg) {
        float v = psum[hl][reg];
        v += __shfl_xor(v, 1, 64);
        v += __shfl_xor(v, 2, 64);
        v += __shfl_xor(v, 4, 64);
        v += __shfl_xor(v, 8, 64);
        if (m == 0) ltile[r16 + kb * 4 + reg][4 * (w >> 1) + hl] = v;
      }
    }
  }
  __syncthreads();
  {
    int el = t >> 3, hh = t & 7;
    int i = i0 + el;
    if (i < NE) {
      float lg = ltile[el][hh];
      logits[((size_t)tag * NE + i) * NH + hh] = lg;
      atomicMax(&mkey[tag * NN * NH + ed_s[el] * NH + hh], encf(lg));
    }
  }
}

// ---------- K5: ex = exp(logit - m[dst]); den = segment_sum (sorted order) ----------
__global__ void k5_ex(const float* __restrict__ logits, const u32* __restrict__ mkey,
                      const int* __restrict__ sdst, float* __restrict__ ex, float* __restrict__ den)
{
  int idx = blockIdx.x * 256 + threadIdx.x;
  if (idx >= 2 * NE * NH) return;
  int h = idx & 7;
  int e = (idx >> 3) % NE;
  int tag = idx / (NE * NH);
  int d = sdst[e];
  float m = decf(mkey[tag * NN * NH + d * NH + h]);
  float v = __expf(logits[idx] - m);
  ex[idx] = v;
  atomicAdd(&den[tag * NN * NH + d * NH + h], v);
}

// ---------- K6: per-edge main (sorted, contiguous P) ----------
__global__ __launch_bounds__(256) void k6_main(const u32* __restrict__ P32,
                                               const float* __restrict__ wig,
                                               const u32* __restrict__ h1rad,
                                               const float* __restrict__ wpv,
                                               const float* __restrict__ ex,
                                               const float* __restrict__ den,
                                               const u32* __restrict__ eperm,
                                               const int* __restrict__ ssrc,
                                               const int* __restrict__ sdst,
                                               float* __restrict__ acc)
{
  __shared__ float wigs[4][81];
  __shared__ u32 ep4[4];
  int t = threadIdx.x;
  int tag = blockIdx.y;
  int ib = blockIdx.x * 4;
  if (t < 4) ep4[t] = eperm[ib + t];
  __syncthreads();
  for (int q = t; q < 4 * 81; q += 256) {
    int el = q / 81, j = q % 81;
    wigs[el][j] = wig[(size_t)ep4[el] * 81 + j];
  }
  __syncthreads();
  int wid = t >> 6, lane = t & 63;
  int i = ib + wid;
  int s = ssrc[i], d = sdst[i];
  const u32* rowT = P32 + ((size_t)s * 4 + tag * 2) * 576;
  const u32* rowB = P32 + ((size_t)d * 4 + tag * 2 + 1) * 576;
  float S0[9], S1[9];
  #pragma unroll
  for (int j = 0; j < 9; ++j) {
    u32 ut = rowT[j * 64 + lane];
    u32 ub = rowB[j * 64 + lane];
    S0[j] = bf_lo(ut) + bf_lo(ub);
    S1[j] = bf_hi(ut) + bf_hi(ub);
  }
  float m0[9], m1[9];
  #pragma unroll
  for (int r = 0; r < 9; ++r) {
    float a0 = 0.f, a1 = 0.f;
    #pragma unroll
    for (int j = 0; j < 9; ++j) {
      float w = wigs[wid][r * 9 + j];
      a0 += w * S0[j];
      a1 += w * S1[j];
    }
    m0[r] = a0; m1[r] = a1;
  }
  u32 ur = h1rad[((size_t)tag * NE + i) * 64 + lane];
  float r0v = bf_lo(ur), r1v = bf_hi(ur);
  #pragma unroll
  for (int r = 0; r < 9; ++r) { m0[r] *= r0v; m1[r] *= r1v; }
  float g0 = sigmoidf_(m0[0]);
  float g1 = sigmoidf_(m1[0]);
  float gA = 0.f, gB = 0.f;
  #pragma unroll
  for (int h = 0; h < NH; ++h) {
    float at = ex[((size_t)tag * NE + i) * NH + h]
             / (den[tag * NN * NH + d * NH + h] + 1e-9f);
    gA += wpv[tag * 1024 + (2 * lane) * 8 + h] * at;
    gB += wpv[tag * 1024 + (2 * lane + 1) * 8 + h] * at;
  }
  float sp[9];
  #pragma unroll
  for (int r = 0; r < 9; ++r)
    sp[r] = m0[r] * g0 * gA + m1[r] * g1 * gB;
  #pragma unroll
  for (int off = 1; off < 64; off <<= 1) {
    #pragma unroll
    for (int r = 0; r < 9; ++r)
      sp[r] += __shfl_xor(sp[r], off, 64);
  }
  if (lane < 3) {
    int ip = lane + 1;
    float y = 0.f;
    #pragma unroll
    for (int j = 0; j < 9; ++j)
      y += wigs[wid][j * 9 + ip] * sp[j];
    atomicAdd(&acc[tag * NN * 3 + d * 3 + lane], y);
  }
}

// ---------- K7: masked select, f32 out ----------
__global__ void k7_out(const float* __restrict__ acc, const void* __restrict__ mask,
                       const int* __restrict__ flag, float* __restrict__ out)
{
  int idx = blockIdx.x * 256 + threadIdx.x;
  if (idx >= NN * 3) return;
  int n = idx / 3;
  bool msk;
  if (*flag) msk = ((const unsigned char*)mask)[n] != 0;
  else       msk = ((const int*)mask)[n] != 0;
  out[idx] = msk ? acc[NN * 3 + idx] : acc[idx];
}

extern "C" void kernel_launch(void* const* d_in, const int* in_sizes, int n_in,
                              void* d_out, int out_size, void* d_ws, size_t ws_size,
                              hipStream_t stream)
{
  (void)hipGetLastError();   // clear sticky error state

  bool setup_order = (n_in >= 22) && (in_sizes[3] == NN) && (in_sizes[4] == 2 * NE);
  const float *x, *edist, *wig;
  const int *zn, *eidx;
  const void *mask;
  const float *ae_v, *wr1_v, *wr2_v, *wmsg_v, *wal_v, *av_v, *wval_v, *wproj_v;
  const float *ae_d, *wr1_d, *wr2_d, *wmsg_d, *wal_d, *av_d, *wval_d, *wproj_d;
  x     = (const float*)d_in[0];
  edist = (const float*)d_in[1];
  wig   = (const float*)d_in[2];
  if (setup_order) {
    zn      = (const int*)d_in[3];
    eidx    = (const int*)d_in[4];
    mask    = d_in[5];
    ae_v    = (const float*)d_in[6];   wr1_v  = (const float*)d_in[7];
    wr2_v   = (const float*)d_in[8];   wmsg_v = (const float*)d_in[9];
    wal_v   = (const float*)d_in[10];  av_v   = (const float*)d_in[11];
    wval_v  = (const float*)d_in[12];  wproj_v= (const float*)d_in[13];
    ae_d    = (const float*)d_in[14];  wr1_d  = (const float*)d_in[15];
    wr2_d   = (const float*)d_in[16];  wmsg_d = (const float*)d_in[17];
    wal_d   = (const float*)d_in[18];  av_d   = (const float*)d_in[19];
    wval_d  = (const float*)d_in[20];  wproj_d= (const float*)d_in[21];
  } else {
    ae_v    = (const float*)d_in[3];   wr1_v  = (const float*)d_in[4];
    wr2_v   = (const float*)d_in[5];   wmsg_v = (const float*)d_in[6];
    wal_v   = (const float*)d_in[7];   av_v   = (const float*)d_in[8];
    wval_v  = (const float*)d_in[9];   wproj_v= (const float*)d_in[10];
    ae_d    = (const float*)d_in[11];  wr1_d  = (const float*)d_in[12];
    wr2_d   = (const float*)d_in[13];  wmsg_d = (const float*)d_in[14];
    wal_d   = (const float*)d_in[15];  av_d   = (const float*)d_in[16];
    wval_d  = (const float*)d_in[17];  wproj_d= (const float*)d_in[18];
    zn      = (const int*)d_in[19];
    eidx    = (const int*)d_in[20];
    mask    = d_in[21];
  }

  // ---- workspace layout (bytes) ----
  const size_t OFF_P    = 0;              // 46,080,000
  const size_t OFF_H1   = 46080000;       // 25,600,000
  const size_t OFF_LOG  = 71680000;       //  3,200,000
  const size_t OFF_EX   = 74880000;       //  3,200,000
  const size_t OFF_MK   = 78080000;       //    320,000
  const size_t OFF_DEN  = 78400000;       //    320,000
  const size_t OFF_ACC  = 78720000;       //    120,000
  const size_t OFF_RADZ = 78840000;       //    204,800
  const size_t OFF_WPV  = 79044800;       //      8,192
  const size_t OFF_FLAG = 79052992;       //         64
  const size_t OFF_CNT  = 79053056;       //     20,000
  const size_t OFF_PERM = 79073056;       //    200,000
  const size_t OFF_SSRC = 79273056;       //    200,000
  const size_t OFF_SDST = 79473056;       //    200,000
  const size_t OFF_WTM  = 79673056;       //    131,072
  const size_t OFF_WTA  = 79804128;       //    131,072
  const size_t OFF_WTR1 = 79935200;       //     65,536
  const size_t OFF_WTR2 = 80000736;       //     65,536
  const size_t NEEDED   = 80066272;

  const size_t out_bytes = (size_t)out_size * sizeof(float);

  if (d_ws == nullptr || ws_size < NEEDED) {
    hipMemsetAsync(d_out, 0x66, out_bytes, stream);   // ws-too-small signature
    return;
  }

  char* ws = (char*)d_ws;
  u32*   P32    = (u32*)(ws + OFF_P);
  u32*   h1rad  = (u32*)(ws + OFF_H1);
  float* logits = (float*)(ws + OFF_LOG);
  float* ex     = (float*)(ws + OFF_EX);
  u32*   mkey   = (u32*)(ws + OFF_MK);
  float* den    = (float*)(ws + OFF_DEN);
  float* acc    = (float*)(ws + OFF_ACC);
  float* radz   = (float*)(ws + OFF_RADZ);
  float* wpv    = (float*)(ws + OFF_WPV);
  int*   flag   = (int*)(ws + OFF_FLAG);
  u32*   cnt    = (u32*)(ws + OFF_CNT);
  u32*   eperm  = (u32*)(ws + OFF_PERM);
  int*   ssrc   = (int*)(ws + OFF_SSRC);
  int*   sdst   = (int*)(ws + OFF_SDST);
  u32*   WtM    = (u32*)(ws + OFF_WTM);
  u32*   WtA    = (u32*)(ws + OFF_WTA);
  u32*   WtR1   = (u32*)(ws + OFF_WTR1);
  u32*   WtR2   = (u32*)(ws + OFF_WTR2);

  k0_tables<<<1354, 256, 0, stream>>>(ae_v, wr1_v, ae_d, wr1_d,
                                      wval_v, wproj_v, wval_d, wproj_d,
                                      wmsg_v, wmsg_d, wal_v, wal_d,
                                      wr2_v, wr2_d,
                                      radz, wpv, mkey, den, acc, cnt,
                                      WtM, WtA, WtR1, WtR2);
  k0_flag<<<1, 256, 0, stream>>>((const u32*)mask, flag);
  ks_hist<<<196, 256, 0, stream>>>(eidx, cnt);
  ks_scan<<<1, 256, 0, stream>>>(cnt);
  ks_scatter<<<196, 256, 0, stream>>>(eidx, cnt, eperm, ssrc, sdst);
  k1_nodepre<<<1407, 256, 0, stream>>>(x, WtM, P32);
  k23_rad<<<1563, 256, 0, stream>>>(edist, WtR1, WtR2, eperm, ssrc, sdst,
                                    zn, radz, h1rad);
  k4_logits<<<dim3(1563, 2), 256, 0, stream>>>(P32, wig, h1rad, WtA, av_v, av_d,
                                               eperm, ssrc, sdst, logits, mkey);
  k5_ex<<<3125, 256, 0, stream>>>(logits, mkey, sdst, ex, den);
  k6_main<<<dim3(12500, 2), 256, 0, stream>>>(P32, wig, h1rad, wpv, ex, den,
                                              eperm, ssrc, sdst, acc);
  k7_out<<<59, 256, 0, stream>>>(acc, mask, flag, (float*)d_out);

  if (hipGetLastError() != hipSuccess) {
    hipMemsetAsync(d_out, 0x77, out_bytes, stream);   // launch-failure signature
  }
}

// Round 11
// 449.695 us; speedup vs baseline: 1.2920x; 1.1801x over previous
//
#include <hip/hip_runtime.h>

#define NN 5000
#define NE 50000
#define LL 9
#define CC 128
#define NH 8
#define VCD 16
#define DR 128
#define AE 64
#define MZ 100

typedef unsigned int u32;
typedef unsigned short u16;

typedef __attribute__((ext_vector_type(8))) short bf16x8;
typedef __attribute__((ext_vector_type(4))) float f32x4;

__device__ __forceinline__ bf16x8 as_bf16x8(uint4 v){
  union { uint4 u; bf16x8 b; } x; x.u = v; return x.b;
}

// ---------- bf16 helpers ----------
__device__ __forceinline__ float bf_lo(u32 u){ return __uint_as_float(u << 16); }
__device__ __forceinline__ float bf_hi(u32 u){ return __uint_as_float(u & 0xffff0000u); }
__device__ __forceinline__ u16 f2bf(float f){
  u32 u = __float_as_uint(f);
  u32 r = (u + 0x7fffu + ((u >> 16) & 1u)) >> 16;  // RNE
  return (u16)r;
}
__device__ __forceinline__ u32 pack2(float a, float b){
  return (u32)f2bf(a) | ((u32)f2bf(b) << 16);
}
__device__ __forceinline__ u32 encf(float f){
  u32 u = __float_as_uint(f);
  return (u & 0x80000000u) ? ~u : (u | 0x80000000u);
}
__device__ __forceinline__ float decf(u32 k){
  u32 u = (k & 0x80000000u) ? (k & 0x7fffffffu) : ~k;
  return __uint_as_float(u);
}
__device__ __forceinline__ float sigmoidf_(float x){ return 1.f / (1.f + __expf(-x)); }

// ---------- K0: tables + zero-init + K-major weight transposes for MFMA ----------
__global__ void k0_tables(const float* __restrict__ ae_v, const float* __restrict__ wr1_v,
                          const float* __restrict__ ae_d, const float* __restrict__ wr1_d,
                          const float* __restrict__ wval_v, const float* __restrict__ wproj_v,
                          const float* __restrict__ wval_d, const float* __restrict__ wproj_d,
                          const float* __restrict__ wmsg_v, const float* __restrict__ wmsg_d,
                          const float* __restrict__ wal_v, const float* __restrict__ wal_d,
                          const float* __restrict__ wr2_v, const float* __restrict__ wr2_d,
                          float* __restrict__ radz, float* __restrict__ wpv,
                          u32* __restrict__ mkey, float* __restrict__ den,
                          float* __restrict__ acc, u32* __restrict__ cnt,
                          u32* __restrict__ WtM, u32* __restrict__ WtA,
                          u32* __restrict__ WtR1, u32* __restrict__ WtR2)
{
  int idx = blockIdx.x * 256 + threadIdx.x;
  if (idx < 2 * 2 * MZ * CC) {   // radz[tag][sd][z][c]
    int c = idx & 127;
    int z = (idx >> 7) % MZ;
    int sd = (idx / (128 * MZ)) & 1;
    int tag = idx / (128 * MZ * 2);
    const float* ae = tag ? ae_d : ae_v;
    const float* w  = tag ? wr1_d : wr1_v;
    float s = 0.f;
    for (int a = 0; a < AE; ++a)
      s += ae[z * AE + a] * w[(DR + sd * AE + a) * CC + c];
    radz[idx] = s;
  }
  int i2 = idx - 2 * 2 * MZ * CC;
  if (i2 >= 0 && i2 < 2 * CC * NH) {   // wpv[tag][c][h]
    int h = i2 & 7;
    int c = (i2 >> 3) & 127;
    int tag = i2 >> 10;
    const float* wv = tag ? wval_d : wval_v;
    const float* wp = tag ? wproj_d : wproj_v;
    float s = 0.f;
    for (int q = 0; q < VCD; ++q) s += wv[c * (NH * VCD) + h * VCD + q] * wp[h * VCD + q];
    wpv[i2] = s;
  }
  int i3 = i2 - 2 * CC * NH;
  if (i3 >= 0 && i3 < 2 * NN * NH) mkey[i3] = 0u;
  int i4 = i3 - 2 * NN * NH;
  if (i4 >= 0 && i4 < 2 * NN * NH) den[i4] = 0.f;
  int i5 = i4 - 2 * NN * NH;
  if (i5 >= 0 && i5 < 2 * NN * 3) acc[i5] = 0.f;
  int i6 = i5 - 2 * NN * 3;
  if (i6 >= 0 && i6 < NN) cnt[i6] = 0u;
  int i7 = i6 - NN;
  if (i7 >= 0 && i7 < 4 * 128 * 64) {   // WtM[chunk][col][kp]
    int chunk = i7 >> 13;
    int col = (i7 >> 6) & 127;
    int kp = i7 & 63;
    const float* Wm = (chunk >= 2) ? wmsg_d : wmsg_v;
    int kb = 128 * (chunk & 1);
    WtM[i7] = pack2(Wm[(kb + 2 * kp) * 128 + col], Wm[(kb + 2 * kp + 1) * 128 + col]);
  }
  int i8 = i7 - 4 * 128 * 64;
  if (i8 >= 0 && i8 < 2 * 256 * 64) {   // WtA[tag][col][kp]
    int tag = i8 >> 14;
    int col = (i8 >> 6) & 255;
    int kp = i8 & 63;
    const float* Wa = tag ? wal_d : wal_v;
    WtA[i8] = pack2(Wa[(2 * kp) * 256 + col], Wa[(2 * kp + 1) * 256 + col]);
  }
  int i9 = i8 - 2 * 256 * 64;
  if (i9 >= 0 && i9 < 2 * 128 * 64) {   // WtR1[tag][col][kp]
    int tag = i9 >> 13;
    int col = (i9 >> 6) & 127;
    int kp = i9 & 63;
    const float* W = tag ? wr1_d : wr1_v;
    WtR1[i9] = pack2(W[(2 * kp) * 128 + col], W[(2 * kp + 1) * 128 + col]);
  }
  int i10 = i9 - 2 * 128 * 64;
  if (i10 >= 0 && i10 < 2 * 128 * 64) {   // WtR2[tag][col][kp]
    int tag = i10 >> 13;
    int col = (i10 >> 6) & 127;
    int kp = i10 & 63;
    const float* W = tag ? wr2_d : wr2_v;
    WtR2[i10] = pack2(W[(2 * kp) * 128 + col], W[(2 * kp + 1) * 128 + col]);
  }
}

// ---------- K0b: detect mask storage format ----------
__global__ void k0_flag(const u32* __restrict__ mw, int* __restrict__ flag)
{
  __shared__ int bad;
  if (threadIdx.x == 0) bad = 0;
  __syncthreads();
  int lbad = 0;
  for (int i = threadIdx.x; i < 1248; i += 256)
    if (mw[i] > 1u) lbad = 1;
  if (lbad) bad = 1;
  __syncthreads();
  if (threadIdx.x == 0) *flag = bad;   // 1 => bytes, 0 => int32
}

// ---------- sort: histogram / scan / scatter (counting sort by dst) ----------
__global__ void ks_hist(const int* __restrict__ eidx, u32* __restrict__ cnt)
{
  int idx = blockIdx.x * 256 + threadIdx.x;
  if (idx < NE) atomicAdd(&cnt[eidx[NE + idx]], 1u);
}

__global__ void ks_scan(u32* __restrict__ cnt)   // in-place exclusive prefix, 1 block
{
  __shared__ u32 tsum[256];
  int t = threadIdx.x;
  u32 loc[20];
  u32 s = 0;
  #pragma unroll
  for (int k = 0; k < 20; ++k) {
    int b = t * 20 + k;
    loc[k] = (b < NN) ? cnt[b] : 0u;
    s += loc[k];
  }
  tsum[t] = s;
  __syncthreads();
  for (int off = 1; off < 256; off <<= 1) {
    u32 v = (t >= off) ? tsum[t - off] : 0u;
    __syncthreads();
    tsum[t] += v;
    __syncthreads();
  }
  u32 base = (t == 0) ? 0u : tsum[t - 1];
  #pragma unroll
  for (int k = 0; k < 20; ++k) {
    int b = t * 20 + k;
    if (b < NN) cnt[b] = base;
    base += loc[k];
  }
}

__global__ void ks_scatter(const int* __restrict__ eidx, u32* __restrict__ base,
                           u32* __restrict__ eperm, int* __restrict__ ssrc, int* __restrict__ sdst)
{
  int idx = blockIdx.x * 256 + threadIdx.x;
  if (idx >= NE) return;
  int d = eidx[NE + idx];
  u32 pos = atomicAdd(&base[d], 1u);
  eperm[pos] = (u32)idx;
  ssrc[pos] = eidx[idx];
  sdst[pos] = d;
}

// ---------- K1 (MFMA): P = x @ W_msg halves; 32 rows x 512 cols per block ----------
__global__ __launch_bounds__(256) void k1_nodepre(const float* __restrict__ x,
                                                  const u32* __restrict__ WtM,
                                                  u32* __restrict__ P32)
{
  __shared__ uint4 As4[32 * 17];
  u32* As = (u32*)As4;
  int t = threadIdx.x;
  int row0 = blockIdx.x * 32;
  for (int i = t; i < 32 * 64; i += 256) {
    int r = i >> 6, cp = i & 63;
    int row = row0 + r;
    u32 v = 0u;
    if (row < NN * LL) {
      float2 xv = *(const float2*)(x + (size_t)row * CC + 2 * cp);
      v = pack2(xv.x, xv.y);
    }
    As[r * 68 + cp] = v;
  }
  __syncthreads();
  int w = t >> 6, lane = t & 63;
  int m = lane & 15, kb = lane >> 4;
  int r16 = 16 * (w & 1);
  int cb = 256 * (w >> 1);
  bf16x8 afr[4];
  #pragma unroll
  for (int ks = 0; ks < 4; ++ks)
    afr[ks] = as_bf16x8(*(const uint4*)&As[(r16 + m) * 68 + ks * 16 + kb * 4]);
  int rowbase = row0 + r16;
  for (int ct = 0; ct < 16; ++ct) {
    int col = cb + ct * 16 + m;          // 0..511
    int chunk = col >> 7;
    int cl = col & 127;
    f32x4 accv = {0.f, 0.f, 0.f, 0.f};
    #pragma unroll
    for (int ks = 0; ks < 4; ++ks) {
      bf16x8 bfr = as_bf16x8(*(const uint4*)(WtM + ((size_t)chunk * 128 + cl) * 64 + ks * 16 + kb * 4));
      accv = __builtin_amdgcn_mfma_f32_16x16x32_bf16(afr[ks], bfr, accv, 0, 0, 0);
    }
    #pragma unroll
    for (int reg = 0; reg < 4; ++reg) {
      float v = accv[reg];
      float vv = __shfl_xor(v, 1, 64);
      int row = rowbase + kb * 4 + reg;
      if (((lane & 1) == 0) && row < NN * LL) {
        int n = row / 9, j = row - n * 9;
        P32[((size_t)n * 4 + chunk) * 576 + j * 64 + (cl >> 1)] = pack2(v, vv);
      }
    }
  }
}

// ---------- K23 (MFMA, per-tag grid): rad = W_rad2( silu(edist@W_rad1 + radz) ) ----------
__global__ __launch_bounds__(256) void k23_rad(const float* __restrict__ edist,
                                               const u32* __restrict__ WtR1,
                                               const u32* __restrict__ WtR2,
                                               const u32* __restrict__ eperm,
                                               const int* __restrict__ ssrc,
                                               const int* __restrict__ sdst,
                                               const int* __restrict__ zn,
                                               const float* __restrict__ radz,
                                               u32* __restrict__ h1rad)
{
  __shared__ uint4 As4[32 * 17];
  __shared__ uint4 Hs4[32 * 17];
  u32* As = (u32*)As4;
  u32* Hs = (u32*)Hs4;
  __shared__ int zsS[32], zdS[32];
  __shared__ u32 epS[32];
  int t = threadIdx.x;
  int tag = blockIdx.y;
  int e0 = blockIdx.x * 32;
  if (t < 32) {
    int e = e0 + t;
    u32 ep = 0; int s = 0, d = 0;
    if (e < NE) { ep = eperm[e]; s = ssrc[e]; d = sdst[e]; }
    epS[t] = ep; zsS[t] = zn[s]; zdS[t] = zn[d];
  }
  __syncthreads();
  for (int i = t; i < 32 * 64; i += 256) {
    int r = i >> 6, cp = i & 63;
    u32 v = 0u;
    if (e0 + r < NE) {
      float2 xv = *(const float2*)(edist + (size_t)epS[r] * DR + 2 * cp);
      v = pack2(xv.x, xv.y);
    }
    As[r * 68 + cp] = v;
  }
  __syncthreads();
  int w = t >> 6, lane = t & 63;
  int m = lane & 15, kb = lane >> 4;
  int r16 = 16 * (w & 1);
  int cb = 64 * (w >> 1);
  const float* rz_s = radz + tag * 2 * MZ * CC;
  const float* rz_d = rz_s + MZ * CC;
  {  // GEMM1 + radz + silu -> Hs (bf16)
    bf16x8 afr[4];
    #pragma unroll
    for (int ks = 0; ks < 4; ++ks)
      afr[ks] = as_bf16x8(*(const uint4*)&As[(r16 + m) * 68 + ks * 16 + kb * 4]);
    const u32* B1 = WtR1 + (size_t)tag * 128 * 64;
    #pragma unroll
    for (int ct = 0; ct < 4; ++ct) {
      int col = cb + ct * 16 + m;
      f32x4 accv = {0.f, 0.f, 0.f, 0.f};
      #pragma unroll
      for (int ks = 0; ks < 4; ++ks) {
        bf16x8 bfr = as_bf16x8(*(const uint4*)(B1 + (size_t)col * 64 + ks * 16 + kb * 4));
        accv = __builtin_amdgcn_mfma_f32_16x16x32_bf16(afr[ks], bfr, accv, 0, 0, 0);
      }
      #pragma unroll
      for (int reg = 0; reg < 4; ++reg) {
        int row = r16 + kb * 4 + reg;
        float v = accv[reg] + rz_s[zsS[row] * CC + col] + rz_d[zdS[row] * CC + col];
        v = v * sigmoidf_(v);
        float vv = __shfl_xor(v, 1, 64);
        if ((m & 1) == 0) Hs[row * 68 + (col >> 1)] = pack2(v, vv);
      }
    }
  }
  __syncthreads();
  {  // GEMM2 -> h1rad (bf16, sorted layout)
    bf16x8 afr[4];
    #pragma unroll
    for (int ks = 0; ks < 4; ++ks)
      afr[ks] = as_bf16x8(*(const uint4*)&Hs[(r16 + m) * 68 + ks * 16 + kb * 4]);
    const u32* B2 = WtR2 + (size_t)tag * 128 * 64;
    #pragma unroll
    for (int ct = 0; ct < 4; ++ct) {
      int col = cb + ct * 16 + m;
      f32x4 accv = {0.f, 0.f, 0.f, 0.f};
      #pragma unroll
      for (int ks = 0; ks < 4; ++ks) {
        bf16x8 bfr = as_bf16x8(*(const uint4*)(B2 + (size_t)col * 64 + ks * 16 + kb * 4));
        accv = __builtin_amdgcn_mfma_f32_16x16x32_bf16(afr[ks], bfr, accv, 0, 0, 0);
      }
      #pragma unroll
      for (int reg = 0; reg < 4; ++reg) {
        int row = r16 + kb * 4 + reg;
        int e = e0 + row;
        float v = accv[reg];
        float vv = __shfl_xor(v, 1, 64);
        if (((m & 1) == 0) && e < NE)
          h1rad[((size_t)tag * NE + e) * 64 + (col >> 1)] = pack2(v, vv);
      }
    }
  }
}

// ---------- K4 (MFMA): logits + segment max; 16 thr/edge A-build, 3 waves/EU no-spill ----------
__global__ __launch_bounds__(256, 3) void k4_logits(const u32* __restrict__ P32,
                                                    const float* __restrict__ wig,
                                                    const u32* __restrict__ h1rad,
                                                    const u32* __restrict__ WtA,
                                                    const float* __restrict__ av_v,
                                                    const float* __restrict__ av_d,
                                                    const u32* __restrict__ eperm,
                                                    const int* __restrict__ ssrc,
                                                    const int* __restrict__ sdst,
                                                    float* __restrict__ logits,
                                                    u32* __restrict__ mkey)
{
  __shared__ uint4 As4[32 * 17];
  u32* As = (u32*)As4;
  __shared__ float wig0s[32][9];
  __shared__ int es_s[32], ed_s[32];
  __shared__ u32 ep_s[32];
  __shared__ float ltile[32][8];
  int t = threadIdx.x;
  int tag = blockIdx.y;
  const float* av = tag ? av_d : av_v;      // (8,32)
  int i0 = blockIdx.x * 32;
  if (t < 32) {
    int i = i0 + t;
    int s = 0, d = 0; u32 ep = 0;
    if (i < NE) { s = ssrc[i]; d = sdst[i]; ep = eperm[i]; }
    es_s[t] = s; ed_s[t] = d; ep_s[t] = ep;
  }
  __syncthreads();
  for (int q = t; q < 32 * 9; q += 256) {
    int el = q / 9, j = q % 9;
    wig0s[el][j] = (i0 + el < NE) ? wig[(size_t)ep_s[el] * 81 + j] : 0.f;
  }
  __syncthreads();
  // ---- phase 1: A build, 16 threads/edge x 2 passes (low reg pressure) ----
  #pragma unroll
  for (int pass = 0; pass < 2; ++pass) {
    int el = (t >> 4) + pass * 16;
    int pp = t & 15;                    // owns u32 indices pp*4 .. pp*4+3 (8 channels)
    int i = i0 + el;
    bool ok = (i < NE);
    float m0[8];
    #pragma unroll
    for (int c = 0; c < 8; ++c) m0[c] = 0.f;
    if (ok) {
      const uint4* Ts = (const uint4*)(P32 + ((size_t)es_s[el] * 4 + tag * 2) * 576);
      const uint4* Td = (const uint4*)(P32 + ((size_t)ed_s[el] * 4 + tag * 2 + 1) * 576);
      #pragma unroll
      for (int j = 0; j < 9; ++j) {
        float w = wig0s[el][j];
        uint4 a = Ts[j * 16 + pp];
        uint4 b = Td[j * 16 + pp];
        m0[0] += w * (bf_lo(a.x) + bf_lo(b.x));
        m0[1] += w * (bf_hi(a.x) + bf_hi(b.x));
        m0[2] += w * (bf_lo(a.y) + bf_lo(b.y));
        m0[3] += w * (bf_hi(a.y) + bf_hi(b.y));
        m0[4] += w * (bf_lo(a.z) + bf_lo(b.z));
        m0[5] += w * (bf_hi(a.z) + bf_hi(b.z));
        m0[6] += w * (bf_lo(a.w) + bf_lo(b.w));
        m0[7] += w * (bf_hi(a.w) + bf_hi(b.w));
      }
      uint4 rr = ((const uint4*)(h1rad + ((size_t)tag * NE + i) * 64))[pp];
      m0[0] *= bf_lo(rr.x); m0[1] *= bf_hi(rr.x);
      m0[2] *= bf_lo(rr.y); m0[3] *= bf_hi(rr.y);
      m0[4] *= bf_lo(rr.z); m0[5] *= bf_hi(rr.z);
      m0[6] *= bf_lo(rr.w); m0[7] *= bf_hi(rr.w);
    }
    uint4 v4;
    v4.x = pack2(m0[0], m0[1]);
    v4.y = pack2(m0[2], m0[3]);
    v4.z = pack2(m0[4], m0[5]);
    v4.w = pack2(m0[6], m0[7]);
    *(uint4*)&As[el * 68 + pp * 4] = v4;
  }
  __syncthreads();
  // ---- phase 2: MFMA logits C(32x256) = A(32x128) @ WtA ----
  {
    int w = t >> 6, lane = t & 63;
    int m = lane & 15, kb = lane >> 4;
    int r16 = 16 * (w & 1);
    int cb = 128 * (w >> 1);
    bf16x8 afr[4];
    #pragma unroll
    for (int ks = 0; ks < 4; ++ks)
      afr[ks] = as_bf16x8(*(const uint4*)&As[(r16 + m) * 68 + ks * 16 + kb * 4]);
    const u32* WA = WtA + (size_t)tag * 256 * 64;
    float psum[4][4];
    #pragma unroll
    for (int a = 0; a < 4; ++a)
      #pragma unroll
      for (int b = 0; b < 4; ++b) psum[a][b] = 0.f;
    #pragma unroll
    for (int ct = 0; ct < 8; ++ct) {
      int col = cb + ct * 16 + m;
      f32x4 accv = {0.f, 0.f, 0.f, 0.f};
      #pragma unroll
      for (int ks = 0; ks < 4; ++ks) {
        bf16x8 bfr = as_bf16x8(*(const uint4*)(WA + (size_t)col * 64 + ks * 16 + kb * 4));
        accv = __builtin_amdgcn_mfma_f32_16x16x32_bf16(afr[ks], bfr, accv, 0, 0, 0);
      }
      int hl = ct >> 1;
      float avv = av[(4 * (w >> 1) + hl) * 32 + (ct & 1) * 16 + m];
      #pragma unroll
      for (int reg = 0; reg < 4; ++reg) {
        float aa = accv[reg];
        aa = (aa >= 0.f) ? aa : 0.2f * aa;    // leaky_relu 0.2
        psum[hl][reg] += aa * avv;
      }
    }
    #pragma unroll
    for (int hl = 0; hl < 4; ++hl) {
      #pragma unroll
      for (int reg = 0; reg < 4; ++reg) {
        float v = psum[hl][reg];
        v += __shfl_xor(v, 1, 64);
        v += __shfl_xor(v, 2, 64);
        v += __shfl_xor(v, 4, 64);
        v += __shfl_xor(v, 8, 64);
        if (m == 0) ltile[r16 + kb * 4 + reg][4 * (w >> 1) + hl] = v;
      }
    }
  }
  __syncthreads();
  {
    int el = t >> 3, hh = t & 7;
    int i = i0 + el;
    if (i < NE) {
      float lg = ltile[el][hh];
      logits[((size_t)tag * NE + i) * NH + hh] = lg;
      atomicMax(&mkey[tag * NN * NH + ed_s[el] * NH + hh], encf(lg));
    }
  }
}

// ---------- K5: ex = exp(logit - m[dst]); den = segment_sum (sorted order) ----------
__global__ void k5_ex(const float* __restrict__ logits, const u32* __restrict__ mkey,
                      const int* __restrict__ sdst, float* __restrict__ ex, float* __restrict__ den)
{
  int idx = blockIdx.x * 256 + threadIdx.x;
  if (idx >= 2 * NE * NH) return;
  int h = idx & 7;
  int e = (idx >> 3) % NE;
  int tag = idx / (NE * NH);
  int d = sdst[e];
  float m = decf(mkey[tag * NN * NH + d * NH + h]);
  float v = __expf(logits[idx] - m);
  ex[idx] = v;
  atomicAdd(&den[tag * NN * NH + d * NH + h], v);
}

// ---------- K6: per-edge main (sorted, contiguous P) ----------
__global__ __launch_bounds__(256) void k6_main(const u32* __restrict__ P32,
                                               const float* __restrict__ wig,
                                               const u32* __restrict__ h1rad,
                                               const float* __restrict__ wpv,
                                               const float* __restrict__ ex,
                                               const float* __restrict__ den,
                                               const u32* __restrict__ eperm,
                                               const int* __restrict__ ssrc,
                                               const int* __restrict__ sdst,
                                               float* __restrict__ acc)
{
  __shared__ float wigs[4][81];
  __shared__ u32 ep4[4];
  int t = threadIdx.x;
  int tag = blockIdx.y;
  int ib = blockIdx.x * 4;
  if (t < 4) ep4[t] = eperm[ib + t];
  __syncthreads();
  for (int q = t; q < 4 * 81; q += 256) {
    int el = q / 81, j = q % 81;
    wigs[el][j] = wig[(size_t)ep4[el] * 81 + j];
  }
  __syncthreads();
  int wid = t >> 6, lane = t & 63;
  int i = ib + wid;
  int s = ssrc[i], d = sdst[i];
  const u32* rowT = P32 + ((size_t)s * 4 + tag * 2) * 576;
  const u32* rowB = P32 + ((size_t)d * 4 + tag * 2 + 1) * 576;
  float S0[9], S1[9];
  #pragma unroll
  for (int j = 0; j < 9; ++j) {
    u32 ut = rowT[j * 64 + lane];
    u32 ub = rowB[j * 64 + lane];
    S0[j] = bf_lo(ut) + bf_lo(ub);
    S1[j] = bf_hi(ut) + bf_hi(ub);
  }
  float m0[9], m1[9];
  #pragma unroll
  for (int r = 0; r < 9; ++r) {
    float a0 = 0.f, a1 = 0.f;
    #pragma unroll
    for (int j = 0; j < 9; ++j) {
      float w = wigs[wid][r * 9 + j];
      a0 += w * S0[j];
      a1 += w * S1[j];
    }
    m0[r] = a0; m1[r] = a1;
  }
  u32 ur = h1rad[((size_t)tag * NE + i) * 64 + lane];
  float r0v = bf_lo(ur), r1v = bf_hi(ur);
  #pragma unroll
  for (int r = 0; r < 9; ++r) { m0[r] *= r0v; m1[r] *= r1v; }
  float g0 = sigmoidf_(m0[0]);
  float g1 = sigmoidf_(m1[0]);
  float gA = 0.f, gB = 0.f;
  #pragma unroll
  for (int h = 0; h < NH; ++h) {
    float at = ex[((size_t)tag * NE + i) * NH + h]
             / (den[tag * NN * NH + d * NH + h] + 1e-9f);
    gA += wpv[tag * 1024 + (2 * lane) * 8 + h] * at;
    gB += wpv[tag * 1024 + (2 * lane + 1) * 8 + h] * at;
  }
  float sp[9];
  #pragma unroll
  for (int r = 0; r < 9; ++r)
    sp[r] = m0[r] * g0 * gA + m1[r] * g1 * gB;
  #pragma unroll
  for (int off = 1; off < 64; off <<= 1) {
    #pragma unroll
    for (int r = 0; r < 9; ++r)
      sp[r] += __shfl_xor(sp[r], off, 64);
  }
  if (lane < 3) {
    int ip = lane + 1;
    float y = 0.f;
    #pragma unroll
    for (int j = 0; j < 9; ++j)
      y += wigs[wid][j * 9 + ip] * sp[j];
    atomicAdd(&acc[tag * NN * 3 + d * 3 + lane], y);
  }
}

// ---------- K7: masked select, f32 out ----------
__global__ void k7_out(const float* __restrict__ acc, const void* __restrict__ mask,
                       const int* __restrict__ flag, float* __restrict__ out)
{
  int idx = blockIdx.x * 256 + threadIdx.x;
  if (idx >= NN * 3) return;
  int n = idx / 3;
  bool msk;
  if (*flag) msk = ((const unsigned char*)mask)[n] != 0;
  else       msk = ((const int*)mask)[n] != 0;
  out[idx] = msk ? acc[NN * 3 + idx] : acc[idx];
}

extern "C" void kernel_launch(void* const* d_in, const int* in_sizes, int n_in,
                              void* d_out, int out_size, void* d_ws, size_t ws_size,
                              hipStream_t stream)
{
  (void)hipGetLastError();   // clear sticky error state

  bool setup_order = (n_in >= 22) && (in_sizes[3] == NN) && (in_sizes[4] == 2 * NE);
  const float *x, *edist, *wig;
  const int *zn, *eidx;
  const void *mask;
  const float *ae_v, *wr1_v, *wr2_v, *wmsg_v, *wal_v, *av_v, *wval_v, *wproj_v;
  const float *ae_d, *wr1_d, *wr2_d, *wmsg_d, *wal_d, *av_d, *wval_d, *wproj_d;
  x     = (const float*)d_in[0];
  edist = (const float*)d_in[1];
  wig   = (const float*)d_in[2];
  if (setup_order) {
    zn      = (const int*)d_in[3];
    eidx    = (const int*)d_in[4];
    mask    = d_in[5];
    ae_v    = (const float*)d_in[6];   wr1_v  = (const float*)d_in[7];
    wr2_v   = (const float*)d_in[8];   wmsg_v = (const float*)d_in[9];
    wal_v   = (const float*)d_in[10];  av_v   = (const float*)d_in[11];
    wval_v  = (const float*)d_in[12];  wproj_v= (const float*)d_in[13];
    ae_d    = (const float*)d_in[14];  wr1_d  = (const float*)d_in[15];
    wr2_d   = (const float*)d_in[16];  wmsg_d = (const float*)d_in[17];
    wal_d   = (const float*)d_in[18];  av_d   = (const float*)d_in[19];
    wval_d  = (const float*)d_in[20];  wproj_d= (const float*)d_in[21];
  } else {
    ae_v    = (const float*)d_in[3];   wr1_v  = (const float*)d_in[4];
    wr2_v   = (const float*)d_in[5];   wmsg_v = (const float*)d_in[6];
    wal_v   = (const float*)d_in[7];   av_v   = (const float*)d_in[8];
    wval_v  = (const float*)d_in[9];   wproj_v= (const float*)d_in[10];
    ae_d    = (const float*)d_in[11];  wr1_d  = (const float*)d_in[12];
    wr2_d   = (const float*)d_in[13];  wmsg_d = (const float*)d_in[14];
    wal_d   = (const float*)d_in[15];  av_d   = (const float*)d_in[16];
    wval_d  = (const float*)d_in[17];  wproj_d= (const float*)d_in[18];
    zn      = (const int*)d_in[19];
    eidx    = (const int*)d_in[20];
    mask    = d_in[21];
  }

  // ---- workspace layout (bytes) ----
  const size_t OFF_P    = 0;              // 46,080,000
  const size_t OFF_H1   = 46080000;       // 25,600,000
  const size_t OFF_LOG  = 71680000;       //  3,200,000
  const size_t OFF_EX   = 74880000;       //  3,200,000
  const size_t OFF_MK   = 78080000;       //    320,000
  const size_t OFF_DEN  = 78400000;       //    320,000
  const size_t OFF_ACC  = 78720000;       //    120,000
  const size_t OFF_RADZ = 78840000;       //    204,800
  const size_t OFF_WPV  = 79044800;       //      8,192
  const size_t OFF_FLAG = 79052992;       //         64
  const size_t OFF_CNT  = 79053056;       //     20,000
  const size_t OFF_PERM = 79073056;       //    200,000
  const size_t OFF_SSRC = 79273056;       //    200,000
  const size_t OFF_SDST = 79473056;       //    200,000
  const size_t OFF_WTM  = 79673056;       //    131,072
  const size_t OFF_WTA  = 79804128;       //    131,072
  const size_t OFF_WTR1 = 79935200;       //     65,536
  const size_t OFF_WTR2 = 80000736;       //     65,536
  const size_t NEEDED   = 80066272;

  const size_t out_bytes = (size_t)out_size * sizeof(float);

  if (d_ws == nullptr || ws_size < NEEDED) {
    hipMemsetAsync(d_out, 0x66, out_bytes, stream);   // ws-too-small signature
    return;
  }

  char* ws = (char*)d_ws;
  u32*   P32    = (u32*)(ws + OFF_P);
  u32*   h1rad  = (u32*)(ws + OFF_H1);
  float* logits = (float*)(ws + OFF_LOG);
  float* ex     = (float*)(ws + OFF_EX);
  u32*   mkey   = (u32*)(ws + OFF_MK);
  float* den    = (float*)(ws + OFF_DEN);
  float* acc    = (float*)(ws + OFF_ACC);
  float* radz   = (float*)(ws + OFF_RADZ);
  float* wpv    = (float*)(ws + OFF_WPV);
  int*   flag   = (int*)(ws + OFF_FLAG);
  u32*   cnt    = (u32*)(ws + OFF_CNT);
  u32*   eperm  = (u32*)(ws + OFF_PERM);
  int*   ssrc   = (int*)(ws + OFF_SSRC);
  int*   sdst   = (int*)(ws + OFF_SDST);
  u32*   WtM    = (u32*)(ws + OFF_WTM);
  u32*   WtA    = (u32*)(ws + OFF_WTA);
  u32*   WtR1   = (u32*)(ws + OFF_WTR1);
  u32*   WtR2   = (u32*)(ws + OFF_WTR2);

  k0_tables<<<1354, 256, 0, stream>>>(ae_v, wr1_v, ae_d, wr1_d,
                                      wval_v, wproj_v, wval_d, wproj_d,
                                      wmsg_v, wmsg_d, wal_v, wal_d,
                                      wr2_v, wr2_d,
                                      radz, wpv, mkey, den, acc, cnt,
                                      WtM, WtA, WtR1, WtR2);
  k0_flag<<<1, 256, 0, stream>>>((const u32*)mask, flag);
  ks_hist<<<196, 256, 0, stream>>>(eidx, cnt);
  ks_scan<<<1, 256, 0, stream>>>(cnt);
  ks_scatter<<<196, 256, 0, stream>>>(eidx, cnt, eperm, ssrc, sdst);
  k1_nodepre<<<1407, 256, 0, stream>>>(x, WtM, P32);
  k23_rad<<<dim3(1563, 2), 256, 0, stream>>>(edist, WtR1, WtR2, eperm, ssrc, sdst,
                                             zn, radz, h1rad);
  k4_logits<<<dim3(1563, 2), 256, 0, stream>>>(P32, wig, h1rad, WtA, av_v, av_d,
                                               eperm, ssrc, sdst, logits, mkey);
  k5_ex<<<3125, 256, 0, stream>>>(logits, mkey, sdst, ex, den);
  k6_main<<<dim3(12500, 2), 256, 0, stream>>>(P32, wig, h1rad, wpv, ex, den,
                                              eperm, ssrc, sdst, acc);
  k7_out<<<59, 256, 0, stream>>>(acc, mask, flag, (float*)d_out);

  if (hipGetLastError() != hipSuccess) {
    hipMemsetAsync(d_out, 0x77, out_bytes, stream);   // launch-failure signature
  }
}